// Round 1
// baseline (5026.471 us; speedup 1.0000x reference)
//
#include <hip/hip_runtime.h>
#include <math.h>

#define CC 256
#define KK 80
#define BB 16

// ---- workspace layout (in floats) ----
#define OFF_WT   0           // 589824   : wT[2304][256]
#define OFF_S    589824      // 34816000 : s for all 4 levels
#define OFF_PP   35405824    // 942080   : pooling partials
#define OFF_P    36347904    // 16384    : p[4][16][256]
#define OFF_WEFF 36364288    // 1376256  : weff[4][16][84][256]
#define OFF_BEFF 37740544    // 5376     : beff[4][16][84]
// total 37745920 floats = 150,983,680 bytes

// s bases per level (floats within OFF_S)
// L0: 16*256*6400 = 26214400, L1: 6553600, L2: 1638400, L3: 409600

__global__ __launch_bounds__(256) void transpose_w_kernel(const float* __restrict__ w,
                                                          float* __restrict__ wT) {
    int i = blockIdx.x;   // ci*9 + ky*3 + kx, 0..2303
    int t = threadIdx.x;  // co
    wT[i * 256 + t] = w[t * 2304 + i];
}

template<int H, int W, int TW>
__global__ __launch_bounds__(256) void conv_relu_kernel(
    const float* __restrict__ feat, const float* __restrict__ wT,
    const float* __restrict__ cbias, float* __restrict__ sbuf, float* __restrict__ pp)
{
    constexpr int WTN = W / TW;
    int bid = blockIdx.x;
    int wt = bid % WTN;
    int h  = (bid / WTN) % H;
    int b  = bid / (WTN * H);
    int w0 = wt * TW;
    int t  = threadIdx.x;  // co

    float acc[TW];
#pragma unroll
    for (int p2 = 0; p2 < TW; ++p2) acc[p2] = 0.f;

    const float* wcol = wT + t;
    for (int ci = 0; ci < CC; ++ci) {
        const float* fbase = feat + (b * CC + ci) * (H * W);
#pragma unroll
        for (int ky = 0; ky < 3; ++ky) {
            int hh = h + ky - 1;
            float xr[TW + 2];
            if (hh >= 0 && hh < H) {
                const float* frow = fbase + hh * W + w0;
                xr[0] = (w0 > 0) ? frow[-1] : 0.f;
                if constexpr (TW % 4 == 0) {
#pragma unroll
                    for (int j4 = 0; j4 < TW / 4; ++j4) {
                        float4 v = *(const float4*)(frow + j4 * 4);
                        xr[1 + j4*4] = v.x; xr[2 + j4*4] = v.y;
                        xr[3 + j4*4] = v.z; xr[4 + j4*4] = v.w;
                    }
                } else {
#pragma unroll
                    for (int j2 = 0; j2 < TW / 2; ++j2) {
                        float2 v = *(const float2*)(frow + j2 * 2);
                        xr[1 + j2*2] = v.x; xr[2 + j2*2] = v.y;
                    }
                }
                xr[TW + 1] = (w0 + TW < W) ? frow[TW] : 0.f;
            } else {
#pragma unroll
                for (int j = 0; j < TW + 2; ++j) xr[j] = 0.f;
            }
            const float* wr = wcol + (ci * 9 + ky * 3) * 256;
            float wv0 = wr[0];
            float wv1 = wr[256];
            float wv2 = wr[512];
#pragma unroll
            for (int p2 = 0; p2 < TW; ++p2)
                acc[p2] = fmaf(xr[p2], wv0, fmaf(xr[p2+1], wv1, fmaf(xr[p2+2], wv2, acc[p2])));
        }
    }

    __shared__ float lds[CC][TW + 1];   // +1 pad: conflict-free transpose
    float bv = cbias[t];
    float rowsum = 0.f;
#pragma unroll
    for (int p2 = 0; p2 < TW; ++p2) {
        float v = acc[p2] + bv;
        v = v > 0.f ? v : 0.f;
        lds[t][p2] = v;
        rowsum += v;
    }
    // deterministic pooling partial: one value per (block,co)
    pp[((b * H + h) * WTN + wt) * 256 + t] = rowsum;
    __syncthreads();
    float* sout = sbuf + (b * CC) * (H * W) + h * W + w0;
#pragma unroll 2
    for (int it = 0; it < TW; ++it) {
        int e = it * 256 + t;
        int c = e / TW;
        int w = e - c * TW;
        sout[c * (H * W) + w] = lds[c][w];
    }
}

__global__ __launch_bounds__(256) void pool_kernel(const float* __restrict__ pp,
                                                   float* __restrict__ p) {
    const int rows_[4] = {160, 40, 20, 10};
    const int base_[4] = {0, 655360, 819200, 901120};
    const float inv_[4] = {1.f/6400.f, 1.f/1600.f, 1.f/400.f, 1.f/100.f};
    int lvl = blockIdx.x >> 4;
    int b   = blockIdx.x & 15;
    int t   = threadIdx.x;
    int rows = rows_[lvl];
    const float* src = pp + base_[lvl] + (b * rows) * 256 + t;
    float s = 0.f;
    for (int r = 0; r < rows; ++r) s += src[r * 256];
    p[(lvl * 16 + b) * 256 + t] = s * inv_[lvl];
}

__global__ __launch_bounds__(256) void head_kernel(
    const float* __restrict__ p,
    const float* __restrict__ clsw1, const float* __restrict__ clsb1,
    const float* __restrict__ clsw2, const float* __restrict__ clsb2,
    const float* __restrict__ regw1, const float* __restrict__ regb1,
    const float* __restrict__ regw2, const float* __restrict__ regb2,
    const float* __restrict__ lvlw,  const float* __restrict__ lvlb,
    const float* __restrict__ clsfw, const float* __restrict__ clsfb,
    const float* __restrict__ regfw, const float* __restrict__ regfb,
    float* __restrict__ weff, float* __restrict__ beff)
{
    int lvl = blockIdx.x >> 4;
    int b   = blockIdx.x & 15;
    int t   = threadIdx.x;
    __shared__ float pl[256];
    __shared__ float hcl[64];
    __shared__ float hrl[64];
    __shared__ float lgl[4];
    __shared__ float attl;

    pl[t] = p[(lvl * 16 + b) * 256 + t];
    __syncthreads();

    if (t < 64) {
        float a = clsb1[t];
        const float* wr = clsw1 + t * 256;
        for (int c2 = 0; c2 < 256; ++c2) a = fmaf(pl[c2], wr[c2], a);
        hcl[t] = a > 0.f ? a : 0.f;
    } else if (t < 128) {
        int j = t - 64;
        float a = regb1[j];
        const float* wr = regw1 + j * 256;
        for (int c2 = 0; c2 < 256; ++c2) a = fmaf(pl[c2], wr[c2], a);
        hrl[j] = a > 0.f ? a : 0.f;
    } else if (t < 132) {
        int j = t - 128;
        float a = lvlb[j];
        const float* wr = lvlw + j * 256;
        for (int c2 = 0; c2 < 256; ++c2) a = fmaf(pl[c2], wr[c2], a);
        lgl[j] = a;
    }
    __syncthreads();
    if (t == 0) {
        float m = fmaxf(fmaxf(lgl[0], lgl[1]), fmaxf(lgl[2], lgl[3]));
        float e0 = expf(lgl[0] - m), e1 = expf(lgl[1] - m);
        float e2 = expf(lgl[2] - m), e3 = expf(lgl[3] - m);
        float se = e0 + e1 + e2 + e3;
        float el = (lvl == 0) ? e0 : (lvl == 1) ? e1 : (lvl == 2) ? e2 : e3;
        attl = el / se;
    }
    __syncthreads();
    float att = attl;

    float* wout = weff + (lvl * 16 + b) * 84 * 256;
    for (int it = 0; it < 84; ++it) {
        int e = it * 256 + t;
        if (e < 20480) {
            int k = e >> 8, c2 = e & 255;
            int m = c2 * 80 + k;
            const float* wr = clsw2 + m * 64;
            float a = clsb2[m];
#pragma unroll
            for (int j4 = 0; j4 < 16; ++j4) {
                float4 w4 = *(const float4*)(wr + j4 * 4);
                a = fmaf(hcl[j4*4+0], w4.x, a);
                a = fmaf(hcl[j4*4+1], w4.y, a);
                a = fmaf(hcl[j4*4+2], w4.z, a);
                a = fmaf(hcl[j4*4+3], w4.w, a);
            }
            wout[k * 256 + c2] = att * (clsfw[k * 256 + c2] + a);
        } else {
            int e2 = e - 20480;
            int r = e2 >> 8, c2 = e2 & 255;
            int m = c2 * 4 + r;
            const float* wr = regw2 + m * 64;
            float a = regb2[m];
#pragma unroll
            for (int j4 = 0; j4 < 16; ++j4) {
                float4 w4 = *(const float4*)(wr + j4 * 4);
                a = fmaf(hrl[j4*4+0], w4.x, a);
                a = fmaf(hrl[j4*4+1], w4.y, a);
                a = fmaf(hrl[j4*4+2], w4.z, a);
                a = fmaf(hrl[j4*4+3], w4.w, a);
            }
            wout[(80 + r) * 256 + c2] = att * (regfw[r * 256 + c2] + a);
        }
    }
    if (t < 84) {
        beff[(lvl * 16 + b) * 84 + t] = att * (t < 80 ? clsfb[t] : regfb[t - 80]);
    }
}

__global__ __launch_bounds__(64) void epilogue_kernel(
    const float* __restrict__ ws_s, const float* __restrict__ weff,
    const float* __restrict__ beff, float* __restrict__ out)
{
    int bid = blockIdx.x;
    int lvl, tiles, rem;
    if (bid < 2800)      { lvl = 0; tiles = 25; rem = bid; }
    else if (bid < 3584) { lvl = 1; tiles = 7;  rem = bid - 2800; }
    else if (bid < 3808) { lvl = 2; tiles = 2;  rem = bid - 3584; }
    else                 { lvl = 3; tiles = 1;  rem = bid - 3808; }
    const int npx_[4] = {6400, 1600, 400, 100};
    const int sb_[4]  = {0, 26214400, 32768000, 34406400};
    const int cb_[4]  = {0, 8192000, 10240000, 10752000};
    const int rb_[4]  = {10880000, 11289600, 11392000, 11417600};
    int npx  = npx_[lvl];
    int kg   = rem % 7;
    int tile = (rem / 7) % tiles;
    int b    = rem / (7 * tiles);
    int lane = threadIdx.x;
    int px = tile * 256 + lane * 4;
    if (px >= npx) return;

    const float* sB = ws_s + sb_[lvl] + (b * 256) * npx + px;
    const float* wB = weff + ((lvl * 16 + b) * 84 + kg * 12) * 256;
    float4 acc[12];
#pragma unroll
    for (int j = 0; j < 12; ++j) acc[j] = make_float4(0.f, 0.f, 0.f, 0.f);

    for (int c = 0; c < 256; ++c) {
        float4 sv = *(const float4*)(sB + c * npx);
#pragma unroll
        for (int j = 0; j < 12; ++j) {
            float wv = wB[j * 256 + c];
            acc[j].x = fmaf(sv.x, wv, acc[j].x);
            acc[j].y = fmaf(sv.y, wv, acc[j].y);
            acc[j].z = fmaf(sv.z, wv, acc[j].z);
            acc[j].w = fmaf(sv.w, wv, acc[j].w);
        }
    }
    const float* bB = beff + (lvl * 16 + b) * 84 + kg * 12;
#pragma unroll
    for (int j = 0; j < 12; ++j) {
        int k = kg * 12 + j;
        float bb = bB[j];
        float4 v = make_float4(acc[j].x + bb, acc[j].y + bb, acc[j].z + bb, acc[j].w + bb);
        float* op;
        if (k < 80) op = out + cb_[lvl] + (b * 80 + k) * npx + px;
        else        op = out + rb_[lvl] + (b * 4 + (k - 80)) * npx + px;
        *(float4*)op = v;
    }
}

extern "C" void kernel_launch(void* const* d_in, const int* in_sizes, int n_in,
                              void* d_out, int out_size, void* d_ws, size_t ws_size,
                              hipStream_t stream) {
    (void)in_sizes; (void)n_in; (void)out_size; (void)ws_size;
    const float* feat0  = (const float*)d_in[0];
    const float* feat1  = (const float*)d_in[1];
    const float* feat2  = (const float*)d_in[2];
    const float* feat3  = (const float*)d_in[3];
    const float* conv_w = (const float*)d_in[4];
    const float* conv_b = (const float*)d_in[5];
    const float* clsw1  = (const float*)d_in[6];
    const float* clsb1  = (const float*)d_in[7];
    const float* clsw2  = (const float*)d_in[8];
    const float* clsb2  = (const float*)d_in[9];
    const float* regw1  = (const float*)d_in[10];
    const float* regb1  = (const float*)d_in[11];
    const float* regw2  = (const float*)d_in[12];
    const float* regb2  = (const float*)d_in[13];
    const float* lvlw   = (const float*)d_in[14];
    const float* lvlb   = (const float*)d_in[15];
    const float* clsfw  = (const float*)d_in[16];
    const float* clsfb  = (const float*)d_in[17];
    const float* regfw  = (const float*)d_in[18];
    const float* regfb  = (const float*)d_in[19];

    float* ws   = (float*)d_ws;
    float* wT   = ws + OFF_WT;
    float* sb   = ws + OFF_S;
    float* pp   = ws + OFF_PP;
    float* p    = ws + OFF_P;
    float* weff = ws + OFF_WEFF;
    float* beff = ws + OFF_BEFF;
    float* out  = (float*)d_out;

    hipLaunchKernelGGL(transpose_w_kernel, dim3(2304), dim3(256), 0, stream, conv_w, wT);

    hipLaunchKernelGGL((conv_relu_kernel<80,80,40>), dim3(16*80*2), dim3(256), 0, stream,
                       feat0, wT, conv_b, sb + 0,        pp + 0);
    hipLaunchKernelGGL((conv_relu_kernel<40,40,40>), dim3(16*40),   dim3(256), 0, stream,
                       feat1, wT, conv_b, sb + 26214400, pp + 655360);
    hipLaunchKernelGGL((conv_relu_kernel<20,20,20>), dim3(16*20),   dim3(256), 0, stream,
                       feat2, wT, conv_b, sb + 32768000, pp + 819200);
    hipLaunchKernelGGL((conv_relu_kernel<10,10,10>), dim3(16*10),   dim3(256), 0, stream,
                       feat3, wT, conv_b, sb + 34406400, pp + 901120);

    hipLaunchKernelGGL(pool_kernel, dim3(64), dim3(256), 0, stream, pp, p);
    hipLaunchKernelGGL(head_kernel, dim3(64), dim3(256), 0, stream, p,
                       clsw1, clsb1, clsw2, clsb2, regw1, regb1, regw2, regb2,
                       lvlw, lvlb, clsfw, clsfb, regfw, regfb, weff, beff);
    hipLaunchKernelGGL(epilogue_kernel, dim3(3920), dim3(64), 0, stream, sb, weff, beff, out);
}

// Round 6
// 4782.301 us; speedup vs baseline: 1.0511x; 1.0511x over previous
//
#include <hip/hip_runtime.h>
#include <math.h>

typedef unsigned int uint32;

#define CC 256

// ---- workspace layout (BYTES) ----
#define OFFB_WT   0LL           // 2,359,296  : wT[2304][256] f32 (round-1 proven layout)
#define OFFB_S    4194304LL     // 69,632,000 : s bf16 [lvl][b][256][H*W]
#define OFFB_P    73826304LL    // 65,536     : p[4][16][256] f32
#define OFFB_WEFF 73891840LL    // 2,752,512  : weffT[4][16][256][84] bf16
#define OFFB_BEFF 76644352LL    // 21,504     : beff f32
// end = 76,665,856 bytes (well under proven-available ~150.9 MB)

__device__ inline unsigned short f2bf(float f) {
    uint32 u = __float_as_uint(f);
    uint32 r = (u + 0x7fffu + ((u >> 16) & 1u)) >> 16;
    return (unsigned short)r;
}
__device__ inline float bf_lo(uint32 u) { return __uint_as_float(u << 16); }
__device__ inline float bf_hi(uint32 u) { return __uint_as_float(u & 0xffff0000u); }

// ---------- round-1 proven: wT[ci*9+tap][co] = w[co][ci][tap] ----------
__global__ __launch_bounds__(256) void transpose_w_kernel(const float* __restrict__ w,
                                                          float* __restrict__ wT) {
    int i = blockIdx.x;   // ci*9 + ky*3 + kx, 0..2303
    int t = threadIdx.x;  // co
    wT[i * 256 + t] = w[t * 2304 + i];
}

// ---------- round-1 proven fp32 direct conv; ONLY change: bf16 store, no pp ----------
template<int H, int W, int TW>
__global__ __launch_bounds__(256) void conv_relu_kernel(
    const float* __restrict__ feat, const float* __restrict__ wT,
    const float* __restrict__ cbias, unsigned short* __restrict__ sbuf)
{
    constexpr int WTN = W / TW;
    int bid = blockIdx.x;
    int wt = bid % WTN;
    int h  = (bid / WTN) % H;
    int b  = bid / (WTN * H);
    int w0 = wt * TW;
    int t  = threadIdx.x;  // co

    float acc[TW];
#pragma unroll
    for (int p2 = 0; p2 < TW; ++p2) acc[p2] = 0.f;

    const float* wcol = wT + t;
    for (int ci = 0; ci < CC; ++ci) {
        const float* fbase = feat + (b * CC + ci) * (H * W);
#pragma unroll
        for (int ky = 0; ky < 3; ++ky) {
            int hh = h + ky - 1;
            float xr[TW + 2];
            if (hh >= 0 && hh < H) {
                const float* frow = fbase + hh * W + w0;
                xr[0] = (w0 > 0) ? frow[-1] : 0.f;
                if constexpr (TW % 4 == 0) {
#pragma unroll
                    for (int j4 = 0; j4 < TW / 4; ++j4) {
                        float4 v = *(const float4*)(frow + j4 * 4);
                        xr[1 + j4*4] = v.x; xr[2 + j4*4] = v.y;
                        xr[3 + j4*4] = v.z; xr[4 + j4*4] = v.w;
                    }
                } else {
#pragma unroll
                    for (int j2 = 0; j2 < TW / 2; ++j2) {
                        float2 v = *(const float2*)(frow + j2 * 2);
                        xr[1 + j2*2] = v.x; xr[2 + j2*2] = v.y;
                    }
                }
                xr[TW + 1] = (w0 + TW < W) ? frow[TW] : 0.f;
            } else {
#pragma unroll
                for (int j = 0; j < TW + 2; ++j) xr[j] = 0.f;
            }
            const float* wr = wcol + (ci * 9 + ky * 3) * 256;
            float wv0 = wr[0];
            float wv1 = wr[256];
            float wv2 = wr[512];
#pragma unroll
            for (int p2 = 0; p2 < TW; ++p2)
                acc[p2] = fmaf(xr[p2], wv0, fmaf(xr[p2+1], wv1, fmaf(xr[p2+2], wv2, acc[p2])));
        }
    }

    __shared__ float lds[CC][TW + 1];
    float bv = cbias[t];
#pragma unroll
    for (int p2 = 0; p2 < TW; ++p2) {
        float v = acc[p2] + bv;
        lds[t][p2] = v > 0.f ? v : 0.f;
    }
    __syncthreads();
    unsigned short* sout = sbuf + ((size_t)b * CC) * (H * W) + (size_t)h * W + w0;
#pragma unroll 2
    for (int it = 0; it < TW; ++it) {
        int e = it * 256 + t;
        int c = e / TW;
        int w = e - c * TW;
        sout[(size_t)c * (H * W) + w] = f2bf(lds[c][w]);
    }
}

// ---------- round-5 verbatim: pool from bf16 S ----------
__global__ __launch_bounds__(256) void pool2_kernel(const unsigned short* __restrict__ S,
                                                    float* __restrict__ p) {
    const long long sb_[4] = {0LL, 26214400LL, 32768000LL, 34406400LL};
    const int npx_[4] = {6400, 1600, 400, 100};
    const float inv_[4] = {1.f / 6400.f, 1.f / 1600.f, 1.f / 400.f, 1.f / 100.f};
    int bid = blockIdx.x;            // grid 4*16*16 = 1024
    int cg  = bid & 15;
    int b   = (bid >> 4) & 15;
    int lvl = bid >> 8;
    int t   = threadIdx.x;
    int c   = cg * 16 + (t >> 4);
    int l16 = t & 15;
    int npx = npx_[lvl];
    int nq  = npx >> 2;
    const unsigned short* base = S + sb_[lvl] + ((long long)b * 256 + c) * npx;
    float s = 0.f;
    for (int i = l16; i < nq; i += 16) {
        uint2 v = *(const uint2*)(base + i * 4);
        s += bf_lo(v.x) + bf_hi(v.x) + bf_lo(v.y) + bf_hi(v.y);
    }
    s += __shfl_xor(s, 1);
    s += __shfl_xor(s, 2);
    s += __shfl_xor(s, 4);
    s += __shfl_xor(s, 8);
    if (l16 == 0) p[(lvl * 16 + b) * 256 + c] = s * inv_[lvl];
}

// ---------- round-5 verbatim: heads ----------
__global__ __launch_bounds__(256) void head_kernel(
    const float* __restrict__ p,
    const float* __restrict__ clsw1, const float* __restrict__ clsb1,
    const float* __restrict__ clsw2, const float* __restrict__ clsb2,
    const float* __restrict__ regw1, const float* __restrict__ regb1,
    const float* __restrict__ regw2, const float* __restrict__ regb2,
    const float* __restrict__ lvlw,  const float* __restrict__ lvlb,
    const float* __restrict__ clsfw, const float* __restrict__ clsfb,
    const float* __restrict__ regfw, const float* __restrict__ regfb,
    unsigned short* __restrict__ weffT, float* __restrict__ beff)
{
    int lvl = blockIdx.x >> 4;
    int b   = blockIdx.x & 15;
    int t   = threadIdx.x;
    __shared__ float pl[256];
    __shared__ float hcl[64];
    __shared__ float hrl[64];
    __shared__ float lgl[4];
    __shared__ float attl;

    pl[t] = p[(lvl * 16 + b) * 256 + t];
    __syncthreads();

    if (t < 64) {
        float a = clsb1[t];
        const float* wr = clsw1 + t * 256;
        for (int c2 = 0; c2 < 256; ++c2) a = fmaf(pl[c2], wr[c2], a);
        hcl[t] = a > 0.f ? a : 0.f;
    } else if (t < 128) {
        int j = t - 64;
        float a = regb1[j];
        const float* wr = regw1 + j * 256;
        for (int c2 = 0; c2 < 256; ++c2) a = fmaf(pl[c2], wr[c2], a);
        hrl[j] = a > 0.f ? a : 0.f;
    } else if (t < 132) {
        int j = t - 128;
        float a = lvlb[j];
        const float* wr = lvlw + j * 256;
        for (int c2 = 0; c2 < 256; ++c2) a = fmaf(pl[c2], wr[c2], a);
        lgl[j] = a;
    }
    __syncthreads();
    if (t == 0) {
        float m = fmaxf(fmaxf(lgl[0], lgl[1]), fmaxf(lgl[2], lgl[3]));
        float e0 = expf(lgl[0] - m), e1 = expf(lgl[1] - m);
        float e2 = expf(lgl[2] - m), e3 = expf(lgl[3] - m);
        float se = e0 + e1 + e2 + e3;
        float el = (lvl == 0) ? e0 : (lvl == 1) ? e1 : (lvl == 2) ? e2 : e3;
        attl = el / se;
    }
    __syncthreads();
    float att = attl;

    unsigned short* wout = weffT + (size_t)(lvl * 16 + b) * 84 * 256;
    for (int it = 0; it < 84; ++it) {
        int e = it * 256 + t;
        if (e < 20480) {
            int k = e >> 8, c2 = e & 255;
            int m = c2 * 80 + k;
            const float* wr = clsw2 + m * 64;
            float a = clsb2[m];
#pragma unroll
            for (int j4 = 0; j4 < 16; ++j4) {
                float4 w4 = *(const float4*)(wr + j4 * 4);
                a = fmaf(hcl[j4 * 4 + 0], w4.x, a);
                a = fmaf(hcl[j4 * 4 + 1], w4.y, a);
                a = fmaf(hcl[j4 * 4 + 2], w4.z, a);
                a = fmaf(hcl[j4 * 4 + 3], w4.w, a);
            }
            wout[c2 * 84 + k] = f2bf(att * (clsfw[k * 256 + c2] + a));
        } else {
            int e2 = e - 20480;
            int r = e2 >> 8, c2 = e2 & 255;
            int m = c2 * 4 + r;
            const float* wr = regw2 + m * 64;
            float a = regb2[m];
#pragma unroll
            for (int j4 = 0; j4 < 16; ++j4) {
                float4 w4 = *(const float4*)(wr + j4 * 4);
                a = fmaf(hrl[j4 * 4 + 0], w4.x, a);
                a = fmaf(hrl[j4 * 4 + 1], w4.y, a);
                a = fmaf(hrl[j4 * 4 + 2], w4.z, a);
                a = fmaf(hrl[j4 * 4 + 3], w4.w, a);
            }
            wout[c2 * 84 + 80 + r] = f2bf(att * (regfw[r * 256 + c2] + a));
        }
    }
    if (t < 84) {
        beff[(lvl * 16 + b) * 84 + t] = att * (t < 80 ? clsfb[t] : regfb[t - 80]);
    }
}

// ---------- round-5 verbatim: epilogue ----------
__global__ __launch_bounds__(64) void epilogue_kernel(
    const unsigned short* __restrict__ sb16, const unsigned short* __restrict__ weffT,
    const float* __restrict__ beff, float* __restrict__ out)
{
    int bid = blockIdx.x;
    int lvl, tiles, rem;
    if (bid < 2800)      { lvl = 0; tiles = 25; rem = bid; }
    else if (bid < 3584) { lvl = 1; tiles = 7;  rem = bid - 2800; }
    else if (bid < 3808) { lvl = 2; tiles = 2;  rem = bid - 3584; }
    else                 { lvl = 3; tiles = 1;  rem = bid - 3808; }
    const int npx_[4] = {6400, 1600, 400, 100};
    const long long sb_[4] = {0LL, 26214400LL, 32768000LL, 34406400LL};
    const int cb_[4]  = {0, 8192000, 10240000, 10752000};
    const int rb_[4]  = {10880000, 11289600, 11392000, 11417600};
    int npx  = npx_[lvl];
    int kg   = rem % 7;
    int tile = (rem / 7) % tiles;
    int b    = rem / (7 * tiles);
    int lane = threadIdx.x;

    __shared__ __align__(16) unsigned short wlds[256 * 12];
    const unsigned short* wsrc = weffT + (size_t)(lvl * 16 + b) * 84 * 256;
    for (int e = lane; e < 256 * 12; e += 64) {
        int c = e / 12, j = e - c * 12;
        wlds[c * 12 + j] = wsrc[c * 84 + kg * 12 + j];
    }
    __syncthreads();

    int px = tile * 256 + lane * 4;
    if (px >= npx) return;

    const unsigned short* sB = sb16 + sb_[lvl] + ((size_t)b * 256) * npx + px;
    float4 acc[12];
#pragma unroll
    for (int j = 0; j < 12; ++j) acc[j] = make_float4(0.f, 0.f, 0.f, 0.f);

    for (int c = 0; c < 256; ++c) {
        uint2 sv = *(const uint2*)(sB + (size_t)c * npx);
        float s0 = bf_lo(sv.x), s1 = bf_hi(sv.x);
        float s2 = bf_lo(sv.y), s3 = bf_hi(sv.y);
        const uint32* wp = (const uint32*)(wlds + c * 12);
#pragma unroll
        for (int jj = 0; jj < 6; ++jj) {
            uint32 u = wp[jj];
            float w0 = bf_lo(u), w1 = bf_hi(u);
            acc[2 * jj].x     = fmaf(s0, w0, acc[2 * jj].x);
            acc[2 * jj].y     = fmaf(s1, w0, acc[2 * jj].y);
            acc[2 * jj].z     = fmaf(s2, w0, acc[2 * jj].z);
            acc[2 * jj].w     = fmaf(s3, w0, acc[2 * jj].w);
            acc[2 * jj + 1].x = fmaf(s0, w1, acc[2 * jj + 1].x);
            acc[2 * jj + 1].y = fmaf(s1, w1, acc[2 * jj + 1].y);
            acc[2 * jj + 1].z = fmaf(s2, w1, acc[2 * jj + 1].z);
            acc[2 * jj + 1].w = fmaf(s3, w1, acc[2 * jj + 1].w);
        }
    }
    const float* bB = beff + (lvl * 16 + b) * 84 + kg * 12;
#pragma unroll
    for (int j = 0; j < 12; ++j) {
        int k = kg * 12 + j;
        float bb = bB[j];
        float4 v = make_float4(acc[j].x + bb, acc[j].y + bb, acc[j].z + bb, acc[j].w + bb);
        float* op;
        if (k < 80) op = out + cb_[lvl] + ((size_t)b * 80 + k) * npx + px;
        else        op = out + rb_[lvl] + ((size_t)b * 4 + (k - 80)) * npx + px;
        *(float4*)op = v;
    }
}

extern "C" void kernel_launch(void* const* d_in, const int* in_sizes, int n_in,
                              void* d_out, int out_size, void* d_ws, size_t ws_size,
                              hipStream_t stream) {
    (void)in_sizes; (void)n_in; (void)out_size; (void)ws_size;
    const float* feat0  = (const float*)d_in[0];
    const float* feat1  = (const float*)d_in[1];
    const float* feat2  = (const float*)d_in[2];
    const float* feat3  = (const float*)d_in[3];
    const float* conv_w = (const float*)d_in[4];
    const float* conv_b = (const float*)d_in[5];
    const float* clsw1  = (const float*)d_in[6];
    const float* clsb1  = (const float*)d_in[7];
    const float* clsw2  = (const float*)d_in[8];
    const float* clsb2  = (const float*)d_in[9];
    const float* regw1  = (const float*)d_in[10];
    const float* regb1  = (const float*)d_in[11];
    const float* regw2  = (const float*)d_in[12];
    const float* regb2  = (const float*)d_in[13];
    const float* lvlw   = (const float*)d_in[14];
    const float* lvlb   = (const float*)d_in[15];
    const float* clsfw  = (const float*)d_in[16];
    const float* clsfb  = (const float*)d_in[17];
    const float* regfw  = (const float*)d_in[18];
    const float* regfb  = (const float*)d_in[19];

    char* ws = (char*)d_ws;
    float*          wT   = (float*)(ws + OFFB_WT);
    unsigned short* S    = (unsigned short*)(ws + OFFB_S);
    float*          p    = (float*)(ws + OFFB_P);
    unsigned short* weff = (unsigned short*)(ws + OFFB_WEFF);
    float*          beff = (float*)(ws + OFFB_BEFF);
    float* out = (float*)d_out;

    // s level bases (elements)
    unsigned short* S0 = S;
    unsigned short* S1 = S + 26214400LL;
    unsigned short* S2 = S + 32768000LL;
    unsigned short* S3 = S + 34406400LL;

    hipLaunchKernelGGL(transpose_w_kernel, dim3(2304), dim3(256), 0, stream, conv_w, wT);

    hipLaunchKernelGGL((conv_relu_kernel<80,80,40>), dim3(16*80*2), dim3(256), 0, stream,
                       feat0, wT, conv_b, S0);
    hipLaunchKernelGGL((conv_relu_kernel<40,40,40>), dim3(16*40),   dim3(256), 0, stream,
                       feat1, wT, conv_b, S1);
    hipLaunchKernelGGL((conv_relu_kernel<20,20,20>), dim3(16*20),   dim3(256), 0, stream,
                       feat2, wT, conv_b, S2);
    hipLaunchKernelGGL((conv_relu_kernel<10,10,10>), dim3(16*10),   dim3(256), 0, stream,
                       feat3, wT, conv_b, S3);

    hipLaunchKernelGGL(pool2_kernel, dim3(1024), dim3(256), 0, stream, S, p);
    hipLaunchKernelGGL(head_kernel, dim3(64), dim3(256), 0, stream, p,
                       clsw1, clsb1, clsw2, clsb2, regw1, regb1, regw2, regb2,
                       lvlw, lvlb, clsfw, clsfb, regfw, regfb, weff, beff);
    hipLaunchKernelGGL(epilogue_kernel, dim3(3920), dim3(64), 0, stream, S, weff, beff, out);
}

// Round 7
// 1450.266 us; speedup vs baseline: 3.4659x; 3.2975x over previous
//
#include <hip/hip_runtime.h>
#include <math.h>

typedef __attribute__((ext_vector_type(8))) short bf16x8;
typedef __attribute__((ext_vector_type(4))) float f32x4;
typedef unsigned int uint32;

// ---- workspace layout (BYTES) ----
#define OFFB_WT2  0LL            // 1,179,648   : WT2[256][2304] bf16
#define OFFB_PT   1179648LL      // 74,678,272  : PT padded-transposed feats bf16
#define OFFB_S    75857920LL     // 69,632,000  : s bf16
#define OFFB_P    145489920LL    // 65,536      : p[4][16][256] f32
#define OFFB_WEFF 145555456LL    // 2,752,512   : weffT[4][16][256][84] bf16
#define OFFB_BEFF 148307968LL    // 21,504      : beff f32
// end = 148,329,472 bytes (round 1 proved >= 150,983,680 available)

// PT element bases: L0 = 16*82*82*256 = 27,541,504 ; L1 = 16*42*42*256 = 7,225,344
// PT0=0  PT1=27,541,504  PT2=34,766,848  PT3=36,749,312

__device__ inline unsigned short f2bf(float f) {
    uint32 u = __float_as_uint(f);
    uint32 r = (u + 0x7fffu + ((u >> 16) & 1u)) >> 16;
    return (unsigned short)r;
}
__device__ inline float bf_lo(uint32 u) { return __uint_as_float(u << 16); }
__device__ inline float bf_hi(uint32 u) { return __uint_as_float(u & 0xffff0000u); }

// ---------- weight prep: WT2[co][half*1152 + tap*128 + ci127] ----------
__global__ __launch_bounds__(256) void prep_w_kernel(const float* __restrict__ w,
                                                     unsigned short* __restrict__ WT2) {
    int co = blockIdx.x, ci = threadIdx.x;
    const float* src = w + ((size_t)co * 256 + ci) * 9;
    unsigned short* dst = WT2 + (size_t)co * 2304 + (ci >> 7) * 1152 + (ci & 127);
#pragma unroll
    for (int tap = 0; tap < 9; ++tap) dst[tap * 128] = f2bf(src[tap]);
}

// ---------- pad + transpose: PT[b][y][x][ci] bf16, zero border ----------
template<int H, int W>
__global__ __launch_bounds__(256) void pad_transpose_kernel(
    const float* __restrict__ feat, unsigned short* __restrict__ PT)
{
    constexpr int WP = W + 2;
    int bid = blockIdx.x;
    int y = bid % (H + 2), b = bid / (H + 2);
    int t = threadIdx.x;
    unsigned short* dst = PT + ((size_t)(b * (H + 2) + y)) * WP * 256;
    if (y == 0 || y == H + 1) {
        for (int e = t; e < WP * 256; e += 256) dst[e] = 0;
        return;
    }
    __shared__ unsigned short lds[256][W + 1];
    const float* src = feat + ((size_t)b * 256) * (H * W) + (size_t)(y - 1) * W;
    for (int e = t; e < 256 * W; e += 256) {
        int ci = e / W, x = e - ci * W;
        lds[ci][x] = f2bf(src[(size_t)ci * H * W + x]);
    }
    __syncthreads();
    for (int e = t; e < WP * 256; e += 256) {
        int x = e >> 8, ci = e & 255;
        dst[e] = (x == 0 || x == W + 1) ? (unsigned short)0 : lds[ci][x - 1];
    }
}

// ---------- conv 3x3 as MFMA implicit GEMM (B direct from global) ----------
template<int H, int W, int NF>
__global__ __launch_bounds__(512) void conv_mfma_kernel(
    const unsigned short* __restrict__ PT,   // [16][H+2][W+2][256]
    const unsigned short* __restrict__ WT2,  // [256][2304]
    const float* __restrict__ cbias,
    unsigned short* __restrict__ sbuf)       // [16][256][H*W] bf16
{
    constexpr int WP = W + 2;
    constexpr int NPX = H * W;

    int bid = blockIdx.x;
    int h = bid % H, b = bid / H;
    int tid = threadIdx.x;
    int lane = tid & 63, wv = tid >> 6;
    int g = lane >> 4, l15 = lane & 15;
    int co0 = wv * 32;

    f32x4 acc[2][NF];
#pragma unroll
    for (int m = 0; m < 2; ++m)
#pragma unroll
        for (int n = 0; n < NF; ++n) acc[m][n] = (f32x4)0.0f;

    const unsigned short* ptrow = PT + (size_t)(b * (H + 2) + h) * WP * 256;
    const unsigned short* wbase0 = WT2 + (size_t)(co0 + l15) * 2304 + g * 8;
    const unsigned short* wbase1 = wbase0 + 16 * 2304;

    for (int half = 0; half < 2; ++half) {
        const unsigned short* pth = ptrow + half * 128;
        const unsigned short* wh0 = wbase0 + half * 1152;
        const unsigned short* wh1 = wbase1 + half * 1152;
#pragma unroll
        for (int ky = 0; ky < 3; ++ky) {
#pragma unroll
            for (int kx = 0; kx < 3; ++kx) {
                int tap = ky * 3 + kx;
                const unsigned short* prow = pth + ((size_t)ky * WP + l15 + kx) * 256 + g * 8;
#pragma unroll
                for (int cs = 0; cs < 4; ++cs) {
                    bf16x8 a0 = *(const bf16x8*)(wh0 + tap * 128 + cs * 32);
                    bf16x8 a1 = *(const bf16x8*)(wh1 + tap * 128 + cs * 32);
#pragma unroll
                    for (int nf = 0; nf < NF; ++nf) {
                        bf16x8 bv = *(const bf16x8*)(prow + (size_t)nf * 16 * 256 + cs * 32);
                        acc[0][nf] = __builtin_amdgcn_mfma_f32_16x16x32_bf16(a0, bv, acc[0][nf], 0, 0, 0);
                        acc[1][nf] = __builtin_amdgcn_mfma_f32_16x16x32_bf16(a1, bv, acc[1][nf], 0, 0, 0);
                    }
                }
            }
        }
    }

    // epilogue: bias + relu + s store (bf16)
    float cb[2][4];
#pragma unroll
    for (int m = 0; m < 2; ++m)
#pragma unroll
        for (int j = 0; j < 4; ++j)
            cb[m][j] = cbias[co0 + m * 16 + g * 4 + j];

    unsigned short* sB = sbuf + (size_t)b * 256 * NPX + (size_t)h * W;
#pragma unroll
    for (int m = 0; m < 2; ++m) {
#pragma unroll
        for (int nf = 0; nf < NF; ++nf) {
            int px = nf * 16 + l15;
            bool ok = (px < W);
#pragma unroll
            for (int j = 0; j < 4; ++j) {
                float v = acc[m][nf][j] + cb[m][j];
                v = v > 0.f ? v : 0.f;
                if (ok) {
                    int co = co0 + m * 16 + g * 4 + j;
                    sB[(size_t)co * NPX + px] = f2bf(v);
                }
            }
        }
    }
}

// ---------- pool from bf16 S (round-6 validated) ----------
__global__ __launch_bounds__(256) void pool2_kernel(const unsigned short* __restrict__ S,
                                                    float* __restrict__ p) {
    const long long sb_[4] = {0LL, 26214400LL, 32768000LL, 34406400LL};
    const int npx_[4] = {6400, 1600, 400, 100};
    const float inv_[4] = {1.f / 6400.f, 1.f / 1600.f, 1.f / 400.f, 1.f / 100.f};
    int bid = blockIdx.x;            // grid 4*16*16 = 1024
    int cg  = bid & 15;
    int b   = (bid >> 4) & 15;
    int lvl = bid >> 8;
    int t   = threadIdx.x;
    int c   = cg * 16 + (t >> 4);
    int l16 = t & 15;
    int npx = npx_[lvl];
    int nq  = npx >> 2;
    const unsigned short* base = S + sb_[lvl] + ((long long)b * 256 + c) * npx;
    float s = 0.f;
    for (int i = l16; i < nq; i += 16) {
        uint2 v = *(const uint2*)(base + i * 4);
        s += bf_lo(v.x) + bf_hi(v.x) + bf_lo(v.y) + bf_hi(v.y);
    }
    s += __shfl_xor(s, 1);
    s += __shfl_xor(s, 2);
    s += __shfl_xor(s, 4);
    s += __shfl_xor(s, 8);
    if (l16 == 0) p[(lvl * 16 + b) * 256 + c] = s * inv_[lvl];
}

// ---------- heads (round-6 validated) ----------
__global__ __launch_bounds__(256) void head_kernel(
    const float* __restrict__ p,
    const float* __restrict__ clsw1, const float* __restrict__ clsb1,
    const float* __restrict__ clsw2, const float* __restrict__ clsb2,
    const float* __restrict__ regw1, const float* __restrict__ regb1,
    const float* __restrict__ regw2, const float* __restrict__ regb2,
    const float* __restrict__ lvlw,  const float* __restrict__ lvlb,
    const float* __restrict__ clsfw, const float* __restrict__ clsfb,
    const float* __restrict__ regfw, const float* __restrict__ regfb,
    unsigned short* __restrict__ weffT, float* __restrict__ beff)
{
    int lvl = blockIdx.x >> 4;
    int b   = blockIdx.x & 15;
    int t   = threadIdx.x;
    __shared__ float pl[256];
    __shared__ float hcl[64];
    __shared__ float hrl[64];
    __shared__ float lgl[4];
    __shared__ float attl;

    pl[t] = p[(lvl * 16 + b) * 256 + t];
    __syncthreads();

    if (t < 64) {
        float a = clsb1[t];
        const float* wr = clsw1 + t * 256;
        for (int c2 = 0; c2 < 256; ++c2) a = fmaf(pl[c2], wr[c2], a);
        hcl[t] = a > 0.f ? a : 0.f;
    } else if (t < 128) {
        int j = t - 64;
        float a = regb1[j];
        const float* wr = regw1 + j * 256;
        for (int c2 = 0; c2 < 256; ++c2) a = fmaf(pl[c2], wr[c2], a);
        hrl[j] = a > 0.f ? a : 0.f;
    } else if (t < 132) {
        int j = t - 128;
        float a = lvlb[j];
        const float* wr = lvlw + j * 256;
        for (int c2 = 0; c2 < 256; ++c2) a = fmaf(pl[c2], wr[c2], a);
        lgl[j] = a;
    }
    __syncthreads();
    if (t == 0) {
        float m = fmaxf(fmaxf(lgl[0], lgl[1]), fmaxf(lgl[2], lgl[3]));
        float e0 = expf(lgl[0] - m), e1 = expf(lgl[1] - m);
        float e2 = expf(lgl[2] - m), e3 = expf(lgl[3] - m);
        float se = e0 + e1 + e2 + e3;
        float el = (lvl == 0) ? e0 : (lvl == 1) ? e1 : (lvl == 2) ? e2 : e3;
        attl = el / se;
    }
    __syncthreads();
    float att = attl;

    unsigned short* wout = weffT + (size_t)(lvl * 16 + b) * 84 * 256;
    for (int it = 0; it < 84; ++it) {
        int e = it * 256 + t;
        if (e < 20480) {
            int k = e >> 8, c2 = e & 255;
            int m = c2 * 80 + k;
            const float* wr = clsw2 + m * 64;
            float a = clsb2[m];
#pragma unroll
            for (int j4 = 0; j4 < 16; ++j4) {
                float4 w4 = *(const float4*)(wr + j4 * 4);
                a = fmaf(hcl[j4 * 4 + 0], w4.x, a);
                a = fmaf(hcl[j4 * 4 + 1], w4.y, a);
                a = fmaf(hcl[j4 * 4 + 2], w4.z, a);
                a = fmaf(hcl[j4 * 4 + 3], w4.w, a);
            }
            wout[c2 * 84 + k] = f2bf(att * (clsfw[k * 256 + c2] + a));
        } else {
            int e2 = e - 20480;
            int r = e2 >> 8, c2 = e2 & 255;
            int m = c2 * 4 + r;
            const float* wr = regw2 + m * 64;
            float a = regb2[m];
#pragma unroll
            for (int j4 = 0; j4 < 16; ++j4) {
                float4 w4 = *(const float4*)(wr + j4 * 4);
                a = fmaf(hrl[j4 * 4 + 0], w4.x, a);
                a = fmaf(hrl[j4 * 4 + 1], w4.y, a);
                a = fmaf(hrl[j4 * 4 + 2], w4.z, a);
                a = fmaf(hrl[j4 * 4 + 3], w4.w, a);
            }
            wout[c2 * 84 + 80 + r] = f2bf(att * (regfw[r * 256 + c2] + a));
        }
    }
    if (t < 84) {
        beff[(lvl * 16 + b) * 84 + t] = att * (t < 80 ? clsfb[t] : regfb[t - 80]);
    }
}

// ---------- epilogue (round-6 validated) ----------
__global__ __launch_bounds__(64) void epilogue_kernel(
    const unsigned short* __restrict__ sb16, const unsigned short* __restrict__ weffT,
    const float* __restrict__ beff, float* __restrict__ out)
{
    int bid = blockIdx.x;
    int lvl, tiles, rem;
    if (bid < 2800)      { lvl = 0; tiles = 25; rem = bid; }
    else if (bid < 3584) { lvl = 1; tiles = 7;  rem = bid - 2800; }
    else if (bid < 3808) { lvl = 2; tiles = 2;  rem = bid - 3584; }
    else                 { lvl = 3; tiles = 1;  rem = bid - 3808; }
    const int npx_[4] = {6400, 1600, 400, 100};
    const long long sb_[4] = {0LL, 26214400LL, 32768000LL, 34406400LL};
    const int cb_[4]  = {0, 8192000, 10240000, 10752000};
    const int rb_[4]  = {10880000, 11289600, 11392000, 11417600};
    int npx  = npx_[lvl];
    int kg   = rem % 7;
    int tile = (rem / 7) % tiles;
    int b    = rem / (7 * tiles);
    int lane = threadIdx.x;

    __shared__ __align__(16) unsigned short wlds[256 * 12];
    const unsigned short* wsrc = weffT + (size_t)(lvl * 16 + b) * 84 * 256;
    for (int e = lane; e < 256 * 12; e += 64) {
        int c = e / 12, j = e - c * 12;
        wlds[c * 12 + j] = wsrc[c * 84 + kg * 12 + j];
    }
    __syncthreads();

    int px = tile * 256 + lane * 4;
    if (px >= npx) return;

    const unsigned short* sB = sb16 + sb_[lvl] + ((size_t)b * 256) * npx + px;
    float4 acc[12];
#pragma unroll
    for (int j = 0; j < 12; ++j) acc[j] = make_float4(0.f, 0.f, 0.f, 0.f);

    for (int c = 0; c < 256; ++c) {
        uint2 sv = *(const uint2*)(sB + (size_t)c * npx);
        float s0 = bf_lo(sv.x), s1 = bf_hi(sv.x);
        float s2 = bf_lo(sv.y), s3 = bf_hi(sv.y);
        const uint32* wp = (const uint32*)(wlds + c * 12);
#pragma unroll
        for (int jj = 0; jj < 6; ++jj) {
            uint32 u = wp[jj];
            float w0 = bf_lo(u), w1 = bf_hi(u);
            acc[2 * jj].x     = fmaf(s0, w0, acc[2 * jj].x);
            acc[2 * jj].y     = fmaf(s1, w0, acc[2 * jj].y);
            acc[2 * jj].z     = fmaf(s2, w0, acc[2 * jj].z);
            acc[2 * jj].w     = fmaf(s3, w0, acc[2 * jj].w);
            acc[2 * jj + 1].x = fmaf(s0, w1, acc[2 * jj + 1].x);
            acc[2 * jj + 1].y = fmaf(s1, w1, acc[2 * jj + 1].y);
            acc[2 * jj + 1].z = fmaf(s2, w1, acc[2 * jj + 1].z);
            acc[2 * jj + 1].w = fmaf(s3, w1, acc[2 * jj + 1].w);
        }
    }
    const float* bB = beff + (lvl * 16 + b) * 84 + kg * 12;
#pragma unroll
    for (int j = 0; j < 12; ++j) {
        int k = kg * 12 + j;
        float bb = bB[j];
        float4 v = make_float4(acc[j].x + bb, acc[j].y + bb, acc[j].z + bb, acc[j].w + bb);
        float* op;
        if (k < 80) op = out + cb_[lvl] + ((size_t)b * 80 + k) * npx + px;
        else        op = out + rb_[lvl] + ((size_t)b * 4 + (k - 80)) * npx + px;
        *(float4*)op = v;
    }
}

extern "C" void kernel_launch(void* const* d_in, const int* in_sizes, int n_in,
                              void* d_out, int out_size, void* d_ws, size_t ws_size,
                              hipStream_t stream) {
    (void)in_sizes; (void)n_in; (void)out_size; (void)ws_size;
    const float* feat0  = (const float*)d_in[0];
    const float* feat1  = (const float*)d_in[1];
    const float* feat2  = (const float*)d_in[2];
    const float* feat3  = (const float*)d_in[3];
    const float* conv_w = (const float*)d_in[4];
    const float* conv_b = (const float*)d_in[5];
    const float* clsw1  = (const float*)d_in[6];
    const float* clsb1  = (const float*)d_in[7];
    const float* clsw2  = (const float*)d_in[8];
    const float* clsb2  = (const float*)d_in[9];
    const float* regw1  = (const float*)d_in[10];
    const float* regb1  = (const float*)d_in[11];
    const float* regw2  = (const float*)d_in[12];
    const float* regb2  = (const float*)d_in[13];
    const float* lvlw   = (const float*)d_in[14];
    const float* lvlb   = (const float*)d_in[15];
    const float* clsfw  = (const float*)d_in[16];
    const float* clsfb  = (const float*)d_in[17];
    const float* regfw  = (const float*)d_in[18];
    const float* regfb  = (const float*)d_in[19];

    char* ws = (char*)d_ws;
    unsigned short* WT2  = (unsigned short*)(ws + OFFB_WT2);
    unsigned short* PT   = (unsigned short*)(ws + OFFB_PT);
    unsigned short* S    = (unsigned short*)(ws + OFFB_S);
    float*          p    = (float*)(ws + OFFB_P);
    unsigned short* weff = (unsigned short*)(ws + OFFB_WEFF);
    float*          beff = (float*)(ws + OFFB_BEFF);
    float* out = (float*)d_out;

    // PT level bases (elements) — FIXED: PT0 needs 16*82*82*256 = 27,541,504
    unsigned short* PT0 = PT;
    unsigned short* PT1 = PT + 27541504LL;
    unsigned short* PT2 = PT + 34766848LL;
    unsigned short* PT3 = PT + 36749312LL;
    // s level bases (elements)
    unsigned short* S0 = S;
    unsigned short* S1 = S + 26214400LL;
    unsigned short* S2 = S + 32768000LL;
    unsigned short* S3 = S + 34406400LL;

    hipLaunchKernelGGL(prep_w_kernel, dim3(256), dim3(256), 0, stream, conv_w, WT2);

    hipLaunchKernelGGL((pad_transpose_kernel<80,80>), dim3(16*82), dim3(256), 0, stream, feat0, PT0);
    hipLaunchKernelGGL((pad_transpose_kernel<40,40>), dim3(16*42), dim3(256), 0, stream, feat1, PT1);
    hipLaunchKernelGGL((pad_transpose_kernel<20,20>), dim3(16*22), dim3(256), 0, stream, feat2, PT2);
    hipLaunchKernelGGL((pad_transpose_kernel<10,10>), dim3(16*12), dim3(256), 0, stream, feat3, PT3);

    hipLaunchKernelGGL((conv_mfma_kernel<80,80,5>), dim3(16*80), dim3(512), 0, stream, PT0, WT2, conv_b, S0);
    hipLaunchKernelGGL((conv_mfma_kernel<40,40,3>), dim3(16*40), dim3(512), 0, stream, PT1, WT2, conv_b, S1);
    hipLaunchKernelGGL((conv_mfma_kernel<20,20,2>), dim3(16*20), dim3(512), 0, stream, PT2, WT2, conv_b, S2);
    hipLaunchKernelGGL((conv_mfma_kernel<10,10,1>), dim3(16*10), dim3(512), 0, stream, PT3, WT2, conv_b, S3);

    hipLaunchKernelGGL(pool2_kernel, dim3(1024), dim3(256), 0, stream, S, p);
    hipLaunchKernelGGL(head_kernel, dim3(64), dim3(256), 0, stream, p,
                       clsw1, clsb1, clsw2, clsb2, regw1, regb1, regw2, regb2,
                       lvlw, lvlb, clsfw, clsfb, regfw, regfb, weff, beff);
    hipLaunchKernelGGL(epilogue_kernel, dim3(3920), dim3(64), 0, stream, S, weff, beff, out);
}

// Round 8
// 697.616 us; speedup vs baseline: 7.2052x; 2.0789x over previous
//
#include <hip/hip_runtime.h>
#include <math.h>

typedef __attribute__((ext_vector_type(8))) short bf16x8;
typedef __attribute__((ext_vector_type(4))) float f32x4;
typedef unsigned int uint32;

// ---- workspace layout (BYTES) ----
#define OFFB_WT3  0LL            // 1,179,648   : WT3[288][256][8] bf16 (k-chunk major)
#define OFFB_PT   1179648LL      // 74,678,272  : PT padded-transposed feats bf16
#define OFFB_S    75857920LL     // 69,632,000  : s bf16
#define OFFB_P    145489920LL    // 65,536      : p[4][16][256] f32
#define OFFB_WEFF 145555456LL    // 2,752,512   : weffT[4][16][256][84] bf16
#define OFFB_BEFF 148307968LL    // 21,504      : beff f32
// end = 148,329,472 bytes

// PT element bases: PT0=0  PT1=27,541,504  PT2=34,766,848  PT3=36,749,312

__device__ inline unsigned short f2bf(float f) {
    uint32 u = __float_as_uint(f);
    uint32 r = (u + 0x7fffu + ((u >> 16) & 1u)) >> 16;
    return (unsigned short)r;
}
__device__ inline float bf_lo(uint32 u) { return __uint_as_float(u << 16); }
__device__ inline float bf_hi(uint32 u) { return __uint_as_float(u & 0xffff0000u); }

// ---------- weight prep: WT3[q][co][j], q=(half*9+tap)*16 + (ci&127)>>3 ----------
__global__ __launch_bounds__(256) void prep_w_kernel(const float* __restrict__ w,
                                                     unsigned short* __restrict__ WT3) {
    int co = blockIdx.x, ci = threadIdx.x;
    int half = ci >> 7, cc = ci & 127, c8 = cc >> 3, j = cc & 7;
    const float* src = w + ((size_t)co * 256 + ci) * 9;
#pragma unroll
    for (int tap = 0; tap < 9; ++tap) {
        int q = (half * 9 + tap) * 16 + c8;
        WT3[((size_t)q * 256 + co) * 8 + j] = f2bf(src[tap]);
    }
}

// ---------- pad + transpose: PT[b][y][x][ci] bf16, zero border ----------
template<int H, int W>
__global__ __launch_bounds__(256) void pad_transpose_kernel(
    const float* __restrict__ feat, unsigned short* __restrict__ PT)
{
    constexpr int WP = W + 2;
    int bid = blockIdx.x;
    int y = bid % (H + 2), b = bid / (H + 2);
    int t = threadIdx.x;
    unsigned short* dst = PT + ((size_t)(b * (H + 2) + y)) * WP * 256;
    if (y == 0 || y == H + 1) {
        for (int e = t; e < WP * 256; e += 256) dst[e] = 0;
        return;
    }
    __shared__ unsigned short lds[256][W + 1];
    const float* src = feat + ((size_t)b * 256) * (H * W) + (size_t)(y - 1) * W;
    for (int e = t; e < 256 * W; e += 256) {
        int ci = e / W, x = e - ci * W;
        lds[ci][x] = f2bf(src[(size_t)ci * H * W + x]);
    }
    __syncthreads();
    for (int e = t; e < WP * 256; e += 256) {
        int x = e >> 8, ci = e & 255;
        dst[e] = (x == 0 || x == W + 1) ? (unsigned short)0 : lds[ci][x - 1];
    }
}

// ---------- conv 3x3 MFMA implicit GEMM, B staged in LDS (XOR swizzle) ----------
template<int H, int W, int NF, int WL>
__global__ __launch_bounds__(512) void conv_mfma_kernel(
    const unsigned short* __restrict__ PT,   // [16][H+2][W+2][256]
    const unsigned short* __restrict__ WT3,  // [288][256][8]
    const float* __restrict__ cbias,
    unsigned short* __restrict__ sbuf)       // [16][256][H*W] bf16
{
    constexpr int WP = W + 2;
    constexpr int NPX = H * W;
    constexpr int SLOTS = 3 * WL * 16;
    __shared__ unsigned short smem[3 * WL * 128];

    int bid = blockIdx.x;
    int h = bid % H, b = bid / H;
    int tid = threadIdx.x;
    int lane = tid & 63, wv = tid >> 6;
    int g = lane >> 4, l15 = lane & 15;
    int co0 = wv * 32;

    f32x4 acc[2][NF];
#pragma unroll
    for (int m = 0; m < 2; ++m)
#pragma unroll
        for (int n = 0; n < NF; ++n) acc[m][n] = (f32x4)0.0f;

    const unsigned short* ptrow = PT + (size_t)(b * (H + 2) + h) * WP * 256;

    for (int half = 0; half < 2; ++half) {
        if (half) __syncthreads();
        // stage 3 padded rows (this ci-half) into LDS, dest-swizzled
        for (int s = tid; s < SLOTS; s += 512) {
            int r = s / (WL * 16);
            int rem = s - r * (WL * 16);
            int x = rem >> 4, cb = rem & 15;
            int xc = x < WP ? x : WP - 1;
            bf16x8 v = *(const bf16x8*)(ptrow + ((size_t)r * WP + xc) * 256 + half * 128 + cb * 8);
            *(bf16x8*)(smem + (((r * WL + x) * 16) + (cb ^ (x & 15))) * 8) = v;
        }
        __syncthreads();

#pragma unroll
        for (int ky = 0; ky < 3; ++ky) {
#pragma unroll
            for (int kx = 0; kx < 3; ++kx) {
#pragma unroll
                for (int cs = 0; cs < 4; ++cs) {
                    int q = (half * 9 + ky * 3 + kx) * 16 + cs * 4 + g;
                    const unsigned short* ap = WT3 + ((size_t)q * 256 + co0 + l15) * 8;
                    bf16x8 a0 = *(const bf16x8*)(ap);
                    bf16x8 a1 = *(const bf16x8*)(ap + 128);
#pragma unroll
                    for (int nf = 0; nf < NF; ++nf) {
                        int xi = nf * 16 + l15 + kx;
                        bf16x8 bv = *(const bf16x8*)(smem +
                            (((ky * WL + xi) * 16) + ((cs * 4 + g) ^ (xi & 15))) * 8);
                        acc[0][nf] = __builtin_amdgcn_mfma_f32_16x16x32_bf16(a0, bv, acc[0][nf], 0, 0, 0);
                        acc[1][nf] = __builtin_amdgcn_mfma_f32_16x16x32_bf16(a1, bv, acc[1][nf], 0, 0, 0);
                    }
                }
            }
        }
    }

    // epilogue: bias + relu + s store (bf16)
    float cb[2][4];
#pragma unroll
    for (int m = 0; m < 2; ++m)
#pragma unroll
        for (int j = 0; j < 4; ++j)
            cb[m][j] = cbias[co0 + m * 16 + g * 4 + j];

    unsigned short* sB = sbuf + (size_t)b * 256 * NPX + (size_t)h * W;
#pragma unroll
    for (int m = 0; m < 2; ++m) {
#pragma unroll
        for (int nf = 0; nf < NF; ++nf) {
            int px = nf * 16 + l15;
            bool ok = (px < W);
#pragma unroll
            for (int j = 0; j < 4; ++j) {
                float v = acc[m][nf][j] + cb[m][j];
                v = v > 0.f ? v : 0.f;
                if (ok) {
                    int co = co0 + m * 16 + g * 4 + j;
                    sB[(size_t)co * NPX + px] = f2bf(v);
                }
            }
        }
    }
}

// ---------- pool from bf16 S (round-6 validated) ----------
__global__ __launch_bounds__(256) void pool2_kernel(const unsigned short* __restrict__ S,
                                                    float* __restrict__ p) {
    const long long sb_[4] = {0LL, 26214400LL, 32768000LL, 34406400LL};
    const int npx_[4] = {6400, 1600, 400, 100};
    const float inv_[4] = {1.f / 6400.f, 1.f / 1600.f, 1.f / 400.f, 1.f / 100.f};
    int bid = blockIdx.x;            // grid 4*16*16 = 1024
    int cg  = bid & 15;
    int b   = (bid >> 4) & 15;
    int lvl = bid >> 8;
    int t   = threadIdx.x;
    int c   = cg * 16 + (t >> 4);
    int l16 = t & 15;
    int npx = npx_[lvl];
    int nq  = npx >> 2;
    const unsigned short* base = S + sb_[lvl] + ((long long)b * 256 + c) * npx;
    float s = 0.f;
    for (int i = l16; i < nq; i += 16) {
        uint2 v = *(const uint2*)(base + i * 4);
        s += bf_lo(v.x) + bf_hi(v.x) + bf_lo(v.y) + bf_hi(v.y);
    }
    s += __shfl_xor(s, 1);
    s += __shfl_xor(s, 2);
    s += __shfl_xor(s, 4);
    s += __shfl_xor(s, 8);
    if (l16 == 0) p[(lvl * 16 + b) * 256 + c] = s * inv_[lvl];
}

// ---------- heads (round-6 validated) ----------
__global__ __launch_bounds__(256) void head_kernel(
    const float* __restrict__ p,
    const float* __restrict__ clsw1, const float* __restrict__ clsb1,
    const float* __restrict__ clsw2, const float* __restrict__ clsb2,
    const float* __restrict__ regw1, const float* __restrict__ regb1,
    const float* __restrict__ regw2, const float* __restrict__ regb2,
    const float* __restrict__ lvlw,  const float* __restrict__ lvlb,
    const float* __restrict__ clsfw, const float* __restrict__ clsfb,
    const float* __restrict__ regfw, const float* __restrict__ regfb,
    unsigned short* __restrict__ weffT, float* __restrict__ beff)
{
    int lvl = blockIdx.x >> 4;
    int b   = blockIdx.x & 15;
    int t   = threadIdx.x;
    __shared__ float pl[256];
    __shared__ float hcl[64];
    __shared__ float hrl[64];
    __shared__ float lgl[4];
    __shared__ float attl;

    pl[t] = p[(lvl * 16 + b) * 256 + t];
    __syncthreads();

    if (t < 64) {
        float a = clsb1[t];
        const float* wr = clsw1 + t * 256;
        for (int c2 = 0; c2 < 256; ++c2) a = fmaf(pl[c2], wr[c2], a);
        hcl[t] = a > 0.f ? a : 0.f;
    } else if (t < 128) {
        int j = t - 64;
        float a = regb1[j];
        const float* wr = regw1 + j * 256;
        for (int c2 = 0; c2 < 256; ++c2) a = fmaf(pl[c2], wr[c2], a);
        hrl[j] = a > 0.f ? a : 0.f;
    } else if (t < 132) {
        int j = t - 128;
        float a = lvlb[j];
        const float* wr = lvlw + j * 256;
        for (int c2 = 0; c2 < 256; ++c2) a = fmaf(pl[c2], wr[c2], a);
        lgl[j] = a;
    }
    __syncthreads();
    if (t == 0) {
        float m = fmaxf(fmaxf(lgl[0], lgl[1]), fmaxf(lgl[2], lgl[3]));
        float e0 = expf(lgl[0] - m), e1 = expf(lgl[1] - m);
        float e2 = expf(lgl[2] - m), e3 = expf(lgl[3] - m);
        float se = e0 + e1 + e2 + e3;
        float el = (lvl == 0) ? e0 : (lvl == 1) ? e1 : (lvl == 2) ? e2 : e3;
        attl = el / se;
    }
    __syncthreads();
    float att = attl;

    unsigned short* wout = weffT + (size_t)(lvl * 16 + b) * 84 * 256;
    for (int it = 0; it < 84; ++it) {
        int e = it * 256 + t;
        if (e < 20480) {
            int k = e >> 8, c2 = e & 255;
            int m = c2 * 80 + k;
            const float* wr = clsw2 + m * 64;
            float a = clsb2[m];
#pragma unroll
            for (int j4 = 0; j4 < 16; ++j4) {
                float4 w4 = *(const float4*)(wr + j4 * 4);
                a = fmaf(hcl[j4 * 4 + 0], w4.x, a);
                a = fmaf(hcl[j4 * 4 + 1], w4.y, a);
                a = fmaf(hcl[j4 * 4 + 2], w4.z, a);
                a = fmaf(hcl[j4 * 4 + 3], w4.w, a);
            }
            wout[c2 * 84 + k] = f2bf(att * (clsfw[k * 256 + c2] + a));
        } else {
            int e2 = e - 20480;
            int r = e2 >> 8, c2 = e2 & 255;
            int m = c2 * 4 + r;
            const float* wr = regw2 + m * 64;
            float a = regb2[m];
#pragma unroll
            for (int j4 = 0; j4 < 16; ++j4) {
                float4 w4 = *(const float4*)(wr + j4 * 4);
                a = fmaf(hrl[j4 * 4 + 0], w4.x, a);
                a = fmaf(hrl[j4 * 4 + 1], w4.y, a);
                a = fmaf(hrl[j4 * 4 + 2], w4.z, a);
                a = fmaf(hrl[j4 * 4 + 3], w4.w, a);
            }
            wout[c2 * 84 + 80 + r] = f2bf(att * (regfw[r * 256 + c2] + a));
        }
    }
    if (t < 84) {
        beff[(lvl * 16 + b) * 84 + t] = att * (t < 80 ? clsfb[t] : regfb[t - 80]);
    }
}

// ---------- epilogue (round-6 validated) ----------
__global__ __launch_bounds__(64) void epilogue_kernel(
    const unsigned short* __restrict__ sb16, const unsigned short* __restrict__ weffT,
    const float* __restrict__ beff, float* __restrict__ out)
{
    int bid = blockIdx.x;
    int lvl, tiles, rem;
    if (bid < 2800)      { lvl = 0; tiles = 25; rem = bid; }
    else if (bid < 3584) { lvl = 1; tiles = 7;  rem = bid - 2800; }
    else if (bid < 3808) { lvl = 2; tiles = 2;  rem = bid - 3584; }
    else                 { lvl = 3; tiles = 1;  rem = bid - 3808; }
    const int npx_[4] = {6400, 1600, 400, 100};
    const long long sb_[4] = {0LL, 26214400LL, 32768000LL, 34406400LL};
    const int cb_[4]  = {0, 8192000, 10240000, 10752000};
    const int rb_[4]  = {10880000, 11289600, 11392000, 11417600};
    int npx  = npx_[lvl];
    int kg   = rem % 7;
    int tile = (rem / 7) % tiles;
    int b    = rem / (7 * tiles);
    int lane = threadIdx.x;

    __shared__ __align__(16) unsigned short wlds[256 * 12];
    const unsigned short* wsrc = weffT + (size_t)(lvl * 16 + b) * 84 * 256;
    for (int e = lane; e < 256 * 12; e += 64) {
        int c = e / 12, j = e - c * 12;
        wlds[c * 12 + j] = wsrc[c * 84 + kg * 12 + j];
    }
    __syncthreads();

    int px = tile * 256 + lane * 4;
    if (px >= npx) return;

    const unsigned short* sB = sb16 + sb_[lvl] + ((size_t)b * 256) * npx + px;
    float4 acc[12];
#pragma unroll
    for (int j = 0; j < 12; ++j) acc[j] = make_float4(0.f, 0.f, 0.f, 0.f);

    for (int c = 0; c < 256; ++c) {
        uint2 sv = *(const uint2*)(sB + (size_t)c * npx);
        float s0 = bf_lo(sv.x), s1 = bf_hi(sv.x);
        float s2 = bf_lo(sv.y), s3 = bf_hi(sv.y);
        const uint32* wp = (const uint32*)(wlds + c * 12);
#pragma unroll
        for (int jj = 0; jj < 6; ++jj) {
            uint32 u = wp[jj];
            float w0 = bf_lo(u), w1 = bf_hi(u);
            acc[2 * jj].x     = fmaf(s0, w0, acc[2 * jj].x);
            acc[2 * jj].y     = fmaf(s1, w0, acc[2 * jj].y);
            acc[2 * jj].z     = fmaf(s2, w0, acc[2 * jj].z);
            acc[2 * jj].w     = fmaf(s3, w0, acc[2 * jj].w);
            acc[2 * jj + 1].x = fmaf(s0, w1, acc[2 * jj + 1].x);
            acc[2 * jj + 1].y = fmaf(s1, w1, acc[2 * jj + 1].y);
            acc[2 * jj + 1].z = fmaf(s2, w1, acc[2 * jj + 1].z);
            acc[2 * jj + 1].w = fmaf(s3, w1, acc[2 * jj + 1].w);
        }
    }
    const float* bB = beff + (lvl * 16 + b) * 84 + kg * 12;
#pragma unroll
    for (int j = 0; j < 12; ++j) {
        int k = kg * 12 + j;
        float bb = bB[j];
        float4 v = make_float4(acc[j].x + bb, acc[j].y + bb, acc[j].z + bb, acc[j].w + bb);
        float* op;
        if (k < 80) op = out + cb_[lvl] + ((size_t)b * 80 + k) * npx + px;
        else        op = out + rb_[lvl] + ((size_t)b * 4 + (k - 80)) * npx + px;
        *(float4*)op = v;
    }
}

extern "C" void kernel_launch(void* const* d_in, const int* in_sizes, int n_in,
                              void* d_out, int out_size, void* d_ws, size_t ws_size,
                              hipStream_t stream) {
    (void)in_sizes; (void)n_in; (void)out_size; (void)ws_size;
    const float* feat0  = (const float*)d_in[0];
    const float* feat1  = (const float*)d_in[1];
    const float* feat2  = (const float*)d_in[2];
    const float* feat3  = (const float*)d_in[3];
    const float* conv_w = (const float*)d_in[4];
    const float* conv_b = (const float*)d_in[5];
    const float* clsw1  = (const float*)d_in[6];
    const float* clsb1  = (const float*)d_in[7];
    const float* clsw2  = (const float*)d_in[8];
    const float* clsb2  = (const float*)d_in[9];
    const float* regw1  = (const float*)d_in[10];
    const float* regb1  = (const float*)d_in[11];
    const float* regw2  = (const float*)d_in[12];
    const float* regb2  = (const float*)d_in[13];
    const float* lvlw   = (const float*)d_in[14];
    const float* lvlb   = (const float*)d_in[15];
    const float* clsfw  = (const float*)d_in[16];
    const float* clsfb  = (const float*)d_in[17];
    const float* regfw  = (const float*)d_in[18];
    const float* regfb  = (const float*)d_in[19];

    char* ws = (char*)d_ws;
    unsigned short* WT3  = (unsigned short*)(ws + OFFB_WT3);
    unsigned short* PT   = (unsigned short*)(ws + OFFB_PT);
    unsigned short* S    = (unsigned short*)(ws + OFFB_S);
    float*          p    = (float*)(ws + OFFB_P);
    unsigned short* weff = (unsigned short*)(ws + OFFB_WEFF);
    float*          beff = (float*)(ws + OFFB_BEFF);
    float* out = (float*)d_out;

    // PT level bases (elements)
    unsigned short* PT0 = PT;
    unsigned short* PT1 = PT + 27541504LL;
    unsigned short* PT2 = PT + 34766848LL;
    unsigned short* PT3 = PT + 36749312LL;
    // s level bases (elements)
    unsigned short* S0 = S;
    unsigned short* S1 = S + 26214400LL;
    unsigned short* S2 = S + 32768000LL;
    unsigned short* S3 = S + 34406400LL;

    hipLaunchKernelGGL(prep_w_kernel, dim3(256), dim3(256), 0, stream, conv_w, WT3);

    hipLaunchKernelGGL((pad_transpose_kernel<80,80>), dim3(16*82), dim3(256), 0, stream, feat0, PT0);
    hipLaunchKernelGGL((pad_transpose_kernel<40,40>), dim3(16*42), dim3(256), 0, stream, feat1, PT1);
    hipLaunchKernelGGL((pad_transpose_kernel<20,20>), dim3(16*22), dim3(256), 0, stream, feat2, PT2);
    hipLaunchKernelGGL((pad_transpose_kernel<10,10>), dim3(16*12), dim3(256), 0, stream, feat3, PT3);

    hipLaunchKernelGGL((conv_mfma_kernel<80,80,5,84>), dim3(16*80), dim3(512), 0, stream, PT0, WT3, conv_b, S0);
    hipLaunchKernelGGL((conv_mfma_kernel<40,40,3,52>), dim3(16*40), dim3(512), 0, stream, PT1, WT3, conv_b, S1);
    hipLaunchKernelGGL((conv_mfma_kernel<20,20,2,36>), dim3(16*20), dim3(512), 0, stream, PT2, WT3, conv_b, S2);
    hipLaunchKernelGGL((conv_mfma_kernel<10,10,1,20>), dim3(16*10), dim3(512), 0, stream, PT3, WT3, conv_b, S3);

    hipLaunchKernelGGL(pool2_kernel, dim3(1024), dim3(256), 0, stream, S, p);
    hipLaunchKernelGGL(head_kernel, dim3(64), dim3(256), 0, stream, p,
                       clsw1, clsb1, clsw2, clsb2, regw1, regb1, regw2, regb2,
                       lvlw, lvlb, clsfw, clsfb, regfw, regfb, weff, beff);
    hipLaunchKernelGGL(epilogue_kernel, dim3(3920), dim3(64), 0, stream, S, weff, beff, out);
}

// Round 9
// 491.097 us; speedup vs baseline: 10.2352x; 1.4205x over previous
//
#include <hip/hip_runtime.h>
#include <math.h>

typedef __attribute__((ext_vector_type(8))) short bf16x8;
typedef __attribute__((ext_vector_type(4))) float f32x4;
typedef unsigned int uint32;

// ---- workspace layout (BYTES) ----
#define OFFB_WT3  0LL            // 1,179,648   : WT3[288][256][8] bf16 (k-chunk major)
#define OFFB_PT   1179648LL      // 74,678,272  : PT padded-transposed feats bf16
#define OFFB_S    75857920LL     // 69,632,000  : s bf16
#define OFFB_P    145489920LL    // 65,536      : p[4][16][256] f32
#define OFFB_WEFF 145555456LL    // 2,752,512   : weffT[4][16][256][84] bf16
#define OFFB_BEFF 148307968LL    // 21,504      : beff f32
#define OFFB_HB   148329472LL    // 34,816      : hb[64][136] f32 {hc[64],hr[64],att}
// end = 148,364,288 bytes

// PT element bases: PT0=0  PT1=27,541,504  PT2=34,766,848  PT3=36,749,312

__device__ inline unsigned short f2bf(float f) {
    uint32 u = __float_as_uint(f);
    uint32 r = (u + 0x7fffu + ((u >> 16) & 1u)) >> 16;
    return (unsigned short)r;
}
__device__ inline float bf_lo(uint32 u) { return __uint_as_float(u << 16); }
__device__ inline float bf_hi(uint32 u) { return __uint_as_float(u & 0xffff0000u); }

// ---------- weight prep: WT3[q][co][j], q=(half*9+tap)*16 + (ci&127)>>3 ----------
__global__ __launch_bounds__(256) void prep_w_kernel(const float* __restrict__ w,
                                                     unsigned short* __restrict__ WT3) {
    int co = blockIdx.x, ci = threadIdx.x;
    int half = ci >> 7, cc = ci & 127, c8 = cc >> 3, j = cc & 7;
    const float* src = w + ((size_t)co * 256 + ci) * 9;
#pragma unroll
    for (int tap = 0; tap < 9; ++tap) {
        int q = (half * 9 + tap) * 16 + c8;
        WT3[((size_t)q * 256 + co) * 8 + j] = f2bf(src[tap]);
    }
}

// ---------- pad + transpose: PT[b][y][x][ci] bf16, zero border ----------
template<int H, int W>
__global__ __launch_bounds__(256) void pad_transpose_kernel(
    const float* __restrict__ feat, unsigned short* __restrict__ PT)
{
    constexpr int WP = W + 2;
    int bid = blockIdx.x;
    int y = bid % (H + 2), b = bid / (H + 2);
    int t = threadIdx.x;
    unsigned short* dst = PT + ((size_t)(b * (H + 2) + y)) * WP * 256;
    if (y == 0 || y == H + 1) {
        for (int e = t; e < WP * 256; e += 256) dst[e] = 0;
        return;
    }
    __shared__ unsigned short lds[256][W + 1];
    const float* src = feat + ((size_t)b * 256) * (H * W) + (size_t)(y - 1) * W;
    for (int e = t; e < 256 * W; e += 256) {
        int ci = e / W, x = e - ci * W;
        lds[ci][x] = f2bf(src[(size_t)ci * H * W + x]);
    }
    __syncthreads();
    for (int e = t; e < WP * 256; e += 256) {
        int x = e >> 8, ci = e & 255;
        dst[e] = (x == 0 || x == W + 1) ? (unsigned short)0 : lds[ci][x - 1];
    }
}

// ---------- conv 3x3 MFMA implicit GEMM, B staged in LDS (XOR swizzle) ----------
template<int H, int W, int NF, int WL>
__global__ __launch_bounds__(512) void conv_mfma_kernel(
    const unsigned short* __restrict__ PT,   // [16][H+2][W+2][256]
    const unsigned short* __restrict__ WT3,  // [288][256][8]
    const float* __restrict__ cbias,
    unsigned short* __restrict__ sbuf)       // [16][256][H*W] bf16
{
    constexpr int WP = W + 2;
    constexpr int NPX = H * W;
    constexpr int SLOTS = 3 * WL * 16;
    __shared__ unsigned short smem[3 * WL * 128];

    int bid = blockIdx.x;
    int h = bid % H, b = bid / H;
    int tid = threadIdx.x;
    int lane = tid & 63, wv = tid >> 6;
    int g = lane >> 4, l15 = lane & 15;
    int co0 = wv * 32;

    f32x4 acc[2][NF];
#pragma unroll
    for (int m = 0; m < 2; ++m)
#pragma unroll
        for (int n = 0; n < NF; ++n) acc[m][n] = (f32x4)0.0f;

    const unsigned short* ptrow = PT + (size_t)(b * (H + 2) + h) * WP * 256;

    for (int half = 0; half < 2; ++half) {
        if (half) __syncthreads();
        for (int s = tid; s < SLOTS; s += 512) {
            int r = s / (WL * 16);
            int rem = s - r * (WL * 16);
            int x = rem >> 4, cb = rem & 15;
            int xc = x < WP ? x : WP - 1;
            bf16x8 v = *(const bf16x8*)(ptrow + ((size_t)r * WP + xc) * 256 + half * 128 + cb * 8);
            *(bf16x8*)(smem + (((r * WL + x) * 16) + (cb ^ (x & 15))) * 8) = v;
        }
        __syncthreads();

#pragma unroll
        for (int ky = 0; ky < 3; ++ky) {
#pragma unroll
            for (int kx = 0; kx < 3; ++kx) {
#pragma unroll
                for (int cs = 0; cs < 4; ++cs) {
                    int q = (half * 9 + ky * 3 + kx) * 16 + cs * 4 + g;
                    const unsigned short* ap = WT3 + ((size_t)q * 256 + co0 + l15) * 8;
                    bf16x8 a0 = *(const bf16x8*)(ap);
                    bf16x8 a1 = *(const bf16x8*)(ap + 128);
#pragma unroll
                    for (int nf = 0; nf < NF; ++nf) {
                        int xi = nf * 16 + l15 + kx;
                        bf16x8 bv = *(const bf16x8*)(smem +
                            (((ky * WL + xi) * 16) + ((cs * 4 + g) ^ (xi & 15))) * 8);
                        acc[0][nf] = __builtin_amdgcn_mfma_f32_16x16x32_bf16(a0, bv, acc[0][nf], 0, 0, 0);
                        acc[1][nf] = __builtin_amdgcn_mfma_f32_16x16x32_bf16(a1, bv, acc[1][nf], 0, 0, 0);
                    }
                }
            }
        }
    }

    float cb[2][4];
#pragma unroll
    for (int m = 0; m < 2; ++m)
#pragma unroll
        for (int j = 0; j < 4; ++j)
            cb[m][j] = cbias[co0 + m * 16 + g * 4 + j];

    unsigned short* sB = sbuf + (size_t)b * 256 * NPX + (size_t)h * W;
#pragma unroll
    for (int m = 0; m < 2; ++m) {
#pragma unroll
        for (int nf = 0; nf < NF; ++nf) {
            int px = nf * 16 + l15;
            bool ok = (px < W);
#pragma unroll
            for (int j = 0; j < 4; ++j) {
                float v = acc[m][nf][j] + cb[m][j];
                v = v > 0.f ? v : 0.f;
                if (ok) {
                    int co = co0 + m * 16 + g * 4 + j;
                    sB[(size_t)co * NPX + px] = f2bf(v);
                }
            }
        }
    }
}

// ---------- pool from bf16 S (round-6 validated) ----------
__global__ __launch_bounds__(256) void pool2_kernel(const unsigned short* __restrict__ S,
                                                    float* __restrict__ p) {
    const long long sb_[4] = {0LL, 26214400LL, 32768000LL, 34406400LL};
    const int npx_[4] = {6400, 1600, 400, 100};
    const float inv_[4] = {1.f / 6400.f, 1.f / 1600.f, 1.f / 400.f, 1.f / 100.f};
    int bid = blockIdx.x;            // grid 4*16*16 = 1024
    int cg  = bid & 15;
    int b   = (bid >> 4) & 15;
    int lvl = bid >> 8;
    int t   = threadIdx.x;
    int c   = cg * 16 + (t >> 4);
    int l16 = t & 15;
    int npx = npx_[lvl];
    int nq  = npx >> 2;
    const unsigned short* base = S + sb_[lvl] + ((long long)b * 256 + c) * npx;
    float s = 0.f;
    for (int i = l16; i < nq; i += 16) {
        uint2 v = *(const uint2*)(base + i * 4);
        s += bf_lo(v.x) + bf_hi(v.x) + bf_lo(v.y) + bf_hi(v.y);
    }
    s += __shfl_xor(s, 1);
    s += __shfl_xor(s, 2);
    s += __shfl_xor(s, 4);
    s += __shfl_xor(s, 8);
    if (l16 == 0) p[(lvl * 16 + b) * 256 + c] = s * inv_[lvl];
}

// ---------- head stage 1: hc/hr/att per (lvl,b) -> hb, beff ----------
__global__ __launch_bounds__(256) void head1_kernel(
    const float* __restrict__ p,
    const float* __restrict__ clsw1, const float* __restrict__ clsb1,
    const float* __restrict__ regw1, const float* __restrict__ regb1,
    const float* __restrict__ lvlw,  const float* __restrict__ lvlb,
    const float* __restrict__ clsfb, const float* __restrict__ regfb,
    float* __restrict__ hb, float* __restrict__ beff)
{
    int lvl = blockIdx.x >> 4;
    int b   = blockIdx.x & 15;
    int t   = threadIdx.x;
    __shared__ float pl[256];
    __shared__ float lgl[4];
    __shared__ float attl;

    pl[t] = p[(lvl * 16 + b) * 256 + t];
    __syncthreads();

    float hval = 0.f;
    if (t < 64) {
        float a = clsb1[t];
        const float* wr = clsw1 + t * 256;
        for (int c2 = 0; c2 < 256; ++c2) a = fmaf(pl[c2], wr[c2], a);
        hval = a > 0.f ? a : 0.f;
    } else if (t < 128) {
        int j = t - 64;
        float a = regb1[j];
        const float* wr = regw1 + j * 256;
        for (int c2 = 0; c2 < 256; ++c2) a = fmaf(pl[c2], wr[c2], a);
        hval = a > 0.f ? a : 0.f;
    } else if (t < 132) {
        int j = t - 128;
        float a = lvlb[j];
        const float* wr = lvlw + j * 256;
        for (int c2 = 0; c2 < 256; ++c2) a = fmaf(pl[c2], wr[c2], a);
        lgl[j] = a;
    }
    __syncthreads();
    if (t == 0) {
        float m = fmaxf(fmaxf(lgl[0], lgl[1]), fmaxf(lgl[2], lgl[3]));
        float e0 = expf(lgl[0] - m), e1 = expf(lgl[1] - m);
        float e2 = expf(lgl[2] - m), e3 = expf(lgl[3] - m);
        float se = e0 + e1 + e2 + e3;
        float el = (lvl == 0) ? e0 : (lvl == 1) ? e1 : (lvl == 2) ? e2 : e3;
        attl = el / se;
    }
    __syncthreads();
    float att = attl;

    size_t base = (size_t)(lvl * 16 + b) * 136;
    if (t < 128) hb[base + t] = hval;
    else if (t == 128) hb[base + 128] = att;
    if (t < 84) {
        beff[(lvl * 16 + b) * 84 + t] = att * (t < 80 ? clsfb[t] : regfb[t - 80]);
    }
}

// ---------- head stage 2: weffT[lb][c][k], one block per channel c ----------
__global__ __launch_bounds__(256) void weff2_kernel(
    const float* __restrict__ hb,
    const float* __restrict__ clsw2, const float* __restrict__ clsb2,
    const float* __restrict__ regw2, const float* __restrict__ regb2,
    const float* __restrict__ clsfw, const float* __restrict__ regfw,
    unsigned short* __restrict__ weffT)
{
    int c = blockIdx.x;      // 0..255
    int t = threadIdx.x;
    __shared__ float wlds[84 * 64];
    __shared__ float hcs[64 * 65];
    __shared__ float hrs[64 * 65];
    __shared__ float atts[64];
    __shared__ float cst[84];

    // stage 84 w2 rows (contiguous in memory)
    {
        const float4* csrc = (const float4*)(clsw2 + (size_t)c * 80 * 64);
        float4* wd = (float4*)wlds;
        for (int e = t; e < 80 * 16; e += 256) wd[e] = csrc[e];
        const float4* rsrc = (const float4*)(regw2 + (size_t)c * 4 * 64);
        for (int e = t; e < 4 * 16; e += 256) wd[80 * 16 + e] = rsrc[e];
    }
    // stage all 64 (hc,hr) vectors, bank-padded
    for (int e = t; e < 64 * 64; e += 256) {
        int lb = e >> 6, j = e & 63;
        hcs[lb * 65 + j] = hb[(size_t)lb * 136 + j];
        hrs[lb * 65 + j] = hb[(size_t)lb * 136 + 64 + j];
    }
    if (t < 64) atts[t] = hb[(size_t)t * 136 + 128];
    if (t < 84) {
        cst[t] = (t < 80) ? (clsb2[(size_t)c * 80 + t] + clsfw[(size_t)t * 256 + c])
                          : (regb2[(size_t)c * 4 + (t - 80)] + regfw[(size_t)(t - 80) * 256 + c]);
    }
    __syncthreads();

    int lb = t & 63;
    int kg0 = t >> 6;    // 0..3
    const float* hc = hcs + lb * 65;
    const float* hr = hrs + lb * 65;
    float att = atts[lb];
    unsigned short* ob = weffT + (size_t)lb * 21504 + (size_t)c * 84;

    for (int kg = kg0; kg < 21; kg += 4) {
        const float* h = (kg == 20) ? hr : hc;
        const float* wr = wlds + kg * 4 * 64;
        float a0 = 0.f, a1 = 0.f, a2 = 0.f, a3 = 0.f;
#pragma unroll
        for (int j = 0; j < 64; ++j) {
            float hj = h[j];
            a0 = fmaf(hj, wr[j], a0);
            a1 = fmaf(hj, wr[64 + j], a1);
            a2 = fmaf(hj, wr[128 + j], a2);
            a3 = fmaf(hj, wr[192 + j], a3);
        }
        int k = kg * 4;
        short4 o;
        o.x = (short)f2bf(att * (cst[k + 0] + a0));
        o.y = (short)f2bf(att * (cst[k + 1] + a1));
        o.z = (short)f2bf(att * (cst[k + 2] + a2));
        o.w = (short)f2bf(att * (cst[k + 3] + a3));
        *(short4*)(ob + k) = o;
    }
}

// ---------- epilogue (round-6 validated) ----------
__global__ __launch_bounds__(64) void epilogue_kernel(
    const unsigned short* __restrict__ sb16, const unsigned short* __restrict__ weffT,
    const float* __restrict__ beff, float* __restrict__ out)
{
    int bid = blockIdx.x;
    int lvl, tiles, rem;
    if (bid < 2800)      { lvl = 0; tiles = 25; rem = bid; }
    else if (bid < 3584) { lvl = 1; tiles = 7;  rem = bid - 2800; }
    else if (bid < 3808) { lvl = 2; tiles = 2;  rem = bid - 3584; }
    else                 { lvl = 3; tiles = 1;  rem = bid - 3808; }
    const int npx_[4] = {6400, 1600, 400, 100};
    const long long sb_[4] = {0LL, 26214400LL, 32768000LL, 34406400LL};
    const int cb_[4]  = {0, 8192000, 10240000, 10752000};
    const int rb_[4]  = {10880000, 11289600, 11392000, 11417600};
    int npx  = npx_[lvl];
    int kg   = rem % 7;
    int tile = (rem / 7) % tiles;
    int b    = rem / (7 * tiles);
    int lane = threadIdx.x;

    __shared__ __align__(16) unsigned short wlds[256 * 12];
    const unsigned short* wsrc = weffT + (size_t)(lvl * 16 + b) * 84 * 256;
    for (int e = lane; e < 256 * 12; e += 64) {
        int c = e / 12, j = e - c * 12;
        wlds[c * 12 + j] = wsrc[c * 84 + kg * 12 + j];
    }
    __syncthreads();

    int px = tile * 256 + lane * 4;
    if (px >= npx) return;

    const unsigned short* sB = sb16 + sb_[lvl] + ((size_t)b * 256) * npx + px;
    float4 acc[12];
#pragma unroll
    for (int j = 0; j < 12; ++j) acc[j] = make_float4(0.f, 0.f, 0.f, 0.f);

    for (int c = 0; c < 256; ++c) {
        uint2 sv = *(const uint2*)(sB + (size_t)c * npx);
        float s0 = bf_lo(sv.x), s1 = bf_hi(sv.x);
        float s2 = bf_lo(sv.y), s3 = bf_hi(sv.y);
        const uint32* wp = (const uint32*)(wlds + c * 12);
#pragma unroll
        for (int jj = 0; jj < 6; ++jj) {
            uint32 u = wp[jj];
            float w0 = bf_lo(u), w1 = bf_hi(u);
            acc[2 * jj].x     = fmaf(s0, w0, acc[2 * jj].x);
            acc[2 * jj].y     = fmaf(s1, w0, acc[2 * jj].y);
            acc[2 * jj].z     = fmaf(s2, w0, acc[2 * jj].z);
            acc[2 * jj].w     = fmaf(s3, w0, acc[2 * jj].w);
            acc[2 * jj + 1].x = fmaf(s0, w1, acc[2 * jj + 1].x);
            acc[2 * jj + 1].y = fmaf(s1, w1, acc[2 * jj + 1].y);
            acc[2 * jj + 1].z = fmaf(s2, w1, acc[2 * jj + 1].z);
            acc[2 * jj + 1].w = fmaf(s3, w1, acc[2 * jj + 1].w);
        }
    }
    const float* bB = beff + (lvl * 16 + b) * 84 + kg * 12;
#pragma unroll
    for (int j = 0; j < 12; ++j) {
        int k = kg * 12 + j;
        float bb = bB[j];
        float4 v = make_float4(acc[j].x + bb, acc[j].y + bb, acc[j].z + bb, acc[j].w + bb);
        float* op;
        if (k < 80) op = out + cb_[lvl] + ((size_t)b * 80 + k) * npx + px;
        else        op = out + rb_[lvl] + ((size_t)b * 4 + (k - 80)) * npx + px;
        *(float4*)op = v;
    }
}

extern "C" void kernel_launch(void* const* d_in, const int* in_sizes, int n_in,
                              void* d_out, int out_size, void* d_ws, size_t ws_size,
                              hipStream_t stream) {
    (void)in_sizes; (void)n_in; (void)out_size; (void)ws_size;
    const float* feat0  = (const float*)d_in[0];
    const float* feat1  = (const float*)d_in[1];
    const float* feat2  = (const float*)d_in[2];
    const float* feat3  = (const float*)d_in[3];
    const float* conv_w = (const float*)d_in[4];
    const float* conv_b = (const float*)d_in[5];
    const float* clsw1  = (const float*)d_in[6];
    const float* clsb1  = (const float*)d_in[7];
    const float* clsw2  = (const float*)d_in[8];
    const float* clsb2  = (const float*)d_in[9];
    const float* regw1  = (const float*)d_in[10];
    const float* regb1  = (const float*)d_in[11];
    const float* regw2  = (const float*)d_in[12];
    const float* regb2  = (const float*)d_in[13];
    const float* lvlw   = (const float*)d_in[14];
    const float* lvlb   = (const float*)d_in[15];
    const float* clsfw  = (const float*)d_in[16];
    const float* clsfb  = (const float*)d_in[17];
    const float* regfw  = (const float*)d_in[18];
    const float* regfb  = (const float*)d_in[19];

    char* ws = (char*)d_ws;
    unsigned short* WT3  = (unsigned short*)(ws + OFFB_WT3);
    unsigned short* PT   = (unsigned short*)(ws + OFFB_PT);
    unsigned short* S    = (unsigned short*)(ws + OFFB_S);
    float*          p    = (float*)(ws + OFFB_P);
    unsigned short* weff = (unsigned short*)(ws + OFFB_WEFF);
    float*          beff = (float*)(ws + OFFB_BEFF);
    float*          hb   = (float*)(ws + OFFB_HB);
    float* out = (float*)d_out;

    unsigned short* PT0 = PT;
    unsigned short* PT1 = PT + 27541504LL;
    unsigned short* PT2 = PT + 34766848LL;
    unsigned short* PT3 = PT + 36749312LL;
    unsigned short* S0 = S;
    unsigned short* S1 = S + 26214400LL;
    unsigned short* S2 = S + 32768000LL;
    unsigned short* S3 = S + 34406400LL;

    hipLaunchKernelGGL(prep_w_kernel, dim3(256), dim3(256), 0, stream, conv_w, WT3);

    hipLaunchKernelGGL((pad_transpose_kernel<80,80>), dim3(16*82), dim3(256), 0, stream, feat0, PT0);
    hipLaunchKernelGGL((pad_transpose_kernel<40,40>), dim3(16*42), dim3(256), 0, stream, feat1, PT1);
    hipLaunchKernelGGL((pad_transpose_kernel<20,20>), dim3(16*22), dim3(256), 0, stream, feat2, PT2);
    hipLaunchKernelGGL((pad_transpose_kernel<10,10>), dim3(16*12), dim3(256), 0, stream, feat3, PT3);

    hipLaunchKernelGGL((conv_mfma_kernel<80,80,5,84>), dim3(16*80), dim3(512), 0, stream, PT0, WT3, conv_b, S0);
    hipLaunchKernelGGL((conv_mfma_kernel<40,40,3,52>), dim3(16*40), dim3(512), 0, stream, PT1, WT3, conv_b, S1);
    hipLaunchKernelGGL((conv_mfma_kernel<20,20,2,36>), dim3(16*20), dim3(512), 0, stream, PT2, WT3, conv_b, S2);
    hipLaunchKernelGGL((conv_mfma_kernel<10,10,1,20>), dim3(16*10), dim3(512), 0, stream, PT3, WT3, conv_b, S3);

    hipLaunchKernelGGL(pool2_kernel, dim3(1024), dim3(256), 0, stream, S, p);
    hipLaunchKernelGGL(head1_kernel, dim3(64), dim3(256), 0, stream, p,
                       clsw1, clsb1, regw1, regb1, lvlw, lvlb, clsfb, regfb, hb, beff);
    hipLaunchKernelGGL(weff2_kernel, dim3(256), dim3(256), 0, stream, hb,
                       clsw2, clsb2, regw2, regb2, clsfw, regfw, weff);
    hipLaunchKernelGGL(epilogue_kernel, dim3(3920), dim3(64), 0, stream, S, weff, beff, out);
}

// Round 10
// 433.781 us; speedup vs baseline: 11.5876x; 1.1321x over previous
//
#include <hip/hip_runtime.h>
#include <math.h>

typedef __attribute__((ext_vector_type(8))) short bf16x8;
typedef __attribute__((ext_vector_type(4))) float f32x4;
typedef unsigned int uint32;

// ---- workspace layout (BYTES) ----
#define OFFB_WT3   0LL           // 1,179,648   : WT3[288][256][8] bf16
#define OFFB_PT    1179648LL     // 74,678,272  : PT padded-transposed feats bf16
#define OFFB_WEFFM 1179648LL     // 3,145,728   : weffM[64][96][256] bf16 (ALIASES PT; written after conv)
#define OFFB_ST    75857920LL    // 69,632,000  : S^T [b][px][c] bf16 per level
#define OFFB_PP    145489920LL   // 2,457,600   : pp[lvl][b][H][256] f32
#define OFFB_P     147947520LL   // 65,536      : p[4][16][256] f32
#define OFFB_BEFF  148013056LL   // 21,504      : beff f32
#define OFFB_HB    148034560LL   // 34,816      : hb[64][136] f32
// end = 148,069,376 bytes (≤ 148,364,288 proven in round 9)

// PT element bases: PT0=0  PT1=27,541,504  PT2=34,766,848  PT3=36,749,312
// ST element bases: ST0=0  ST1=26,214,400  ST2=32,768,000  ST3=34,406,400

__device__ inline unsigned short f2bf(float f) {
    uint32 u = __float_as_uint(f);
    uint32 r = (u + 0x7fffu + ((u >> 16) & 1u)) >> 16;
    return (unsigned short)r;
}

// ---------- weight prep: WT3[q][co][j], q=(half*9+tap)*16 + (ci&127)>>3 ----------
__global__ __launch_bounds__(256) void prep_w_kernel(const float* __restrict__ w,
                                                     unsigned short* __restrict__ WT3) {
    int co = blockIdx.x, ci = threadIdx.x;
    int half = ci >> 7, cc = ci & 127, c8 = cc >> 3, j = cc & 7;
    const float* src = w + ((size_t)co * 256 + ci) * 9;
#pragma unroll
    for (int tap = 0; tap < 9; ++tap) {
        int q = (half * 9 + tap) * 16 + c8;
        WT3[((size_t)q * 256 + co) * 8 + j] = f2bf(src[tap]);
    }
}

// ---------- pad + transpose: PT[b][y][x][ci] bf16, zero border ----------
template<int H, int W>
__global__ __launch_bounds__(256) void pad_transpose_kernel(
    const float* __restrict__ feat, unsigned short* __restrict__ PT)
{
    constexpr int WP = W + 2;
    int bid = blockIdx.x;
    int y = bid % (H + 2), b = bid / (H + 2);
    int t = threadIdx.x;
    unsigned short* dst = PT + ((size_t)(b * (H + 2) + y)) * WP * 256;
    if (y == 0 || y == H + 1) {
        for (int e = t; e < WP * 256; e += 256) dst[e] = 0;
        return;
    }
    __shared__ unsigned short lds[256][W + 1];
    const float* src = feat + ((size_t)b * 256) * (H * W) + (size_t)(y - 1) * W;
    for (int e = t; e < 256 * W; e += 256) {
        int ci = e / W, x = e - ci * W;
        lds[ci][x] = f2bf(src[(size_t)ci * H * W + x]);
    }
    __syncthreads();
    for (int e = t; e < WP * 256; e += 256) {
        int x = e >> 8, ci = e & 255;
        dst[e] = (x == 0 || x == W + 1) ? (unsigned short)0 : lds[ci][x - 1];
    }
}

// ---------- conv 3x3 MFMA implicit GEMM: 4 waves x 64co, fused pool + S^T store ----------
template<int H, int W, int NF, int WL>
__global__ __launch_bounds__(256) void conv_mfma_kernel(
    const unsigned short* __restrict__ PT,   // [16][H+2][W+2][256]
    const unsigned short* __restrict__ WT3,  // [288][256][8]
    const float* __restrict__ cbias,
    unsigned short* __restrict__ ST,         // [16][H*W][256] bf16 (px-major, c-contig)
    float* __restrict__ pp)                  // [16][H][256] f32
{
    constexpr int WP = W + 2;
    constexpr int NPX = H * W;
    constexpr int SLOTS = 3 * WL * 16;
    __shared__ unsigned short smem[3 * WL * 128];

    int bid = blockIdx.x;
    int h = bid % H, b = bid / H;
    int tid = threadIdx.x;
    int lane = tid & 63, wv = tid >> 6;       // 4 waves
    int g = lane >> 4, l15 = lane & 15;
    int co0 = wv * 64;

    f32x4 acc[4][NF];
#pragma unroll
    for (int m = 0; m < 4; ++m)
#pragma unroll
        for (int n = 0; n < NF; ++n) acc[m][n] = (f32x4)0.0f;

    const unsigned short* ptrow = PT + (size_t)(b * (H + 2) + h) * WP * 256;

    for (int half = 0; half < 2; ++half) {
        if (half) __syncthreads();
        for (int s = tid; s < SLOTS; s += 256) {
            int r = s / (WL * 16);
            int rem = s - r * (WL * 16);
            int x = rem >> 4, cb = rem & 15;
            int xc = x < WP ? x : WP - 1;
            bf16x8 v = *(const bf16x8*)(ptrow + ((size_t)r * WP + xc) * 256 + half * 128 + cb * 8);
            *(bf16x8*)(smem + (((r * WL + x) * 16) + (cb ^ (x & 15))) * 8) = v;
        }
        __syncthreads();

#pragma unroll
        for (int ky = 0; ky < 3; ++ky) {
#pragma unroll
            for (int kx = 0; kx < 3; ++kx) {
#pragma unroll
                for (int cs = 0; cs < 4; ++cs) {
                    int q = (half * 9 + ky * 3 + kx) * 16 + cs * 4 + g;
                    const unsigned short* ap = WT3 + ((size_t)q * 256 + co0 + l15) * 8;
                    bf16x8 a0 = *(const bf16x8*)(ap);
                    bf16x8 a1 = *(const bf16x8*)(ap + 128);
                    bf16x8 a2 = *(const bf16x8*)(ap + 256);
                    bf16x8 a3 = *(const bf16x8*)(ap + 384);
#pragma unroll
                    for (int nf = 0; nf < NF; ++nf) {
                        int xi = nf * 16 + l15 + kx;
                        bf16x8 bv = *(const bf16x8*)(smem +
                            (((ky * WL + xi) * 16) + ((cs * 4 + g) ^ (xi & 15))) * 8);
                        acc[0][nf] = __builtin_amdgcn_mfma_f32_16x16x32_bf16(a0, bv, acc[0][nf], 0, 0, 0);
                        acc[1][nf] = __builtin_amdgcn_mfma_f32_16x16x32_bf16(a1, bv, acc[1][nf], 0, 0, 0);
                        acc[2][nf] = __builtin_amdgcn_mfma_f32_16x16x32_bf16(a2, bv, acc[2][nf], 0, 0, 0);
                        acc[3][nf] = __builtin_amdgcn_mfma_f32_16x16x32_bf16(a3, bv, acc[3][nf], 0, 0, 0);
                    }
                }
            }
        }
    }

    float cb4[4][4];
#pragma unroll
    for (int m = 0; m < 4; ++m)
#pragma unroll
        for (int j = 0; j < 4; ++j)
            cb4[m][j] = cbias[co0 + m * 16 + g * 4 + j];

    float rs[4][4];
#pragma unroll
    for (int m = 0; m < 4; ++m)
#pragma unroll
        for (int j = 0; j < 4; ++j) rs[m][j] = 0.f;

    __syncthreads();   // smem reuse for transpose
    unsigned short* lds_t = smem;   // [W][260] shorts

#pragma unroll
    for (int m = 0; m < 4; ++m) {
#pragma unroll
        for (int nf = 0; nf < NF; ++nf) {
            int px = nf * 16 + l15;
            bool ok = (px < W);
            short4 o;
#pragma unroll
            for (int j = 0; j < 4; ++j) {
                float v = acc[m][nf][j] + cb4[m][j];
                v = v > 0.f ? v : 0.f;
                if (ok) rs[m][j] += v;
                ((short*)&o)[j] = (short)f2bf(v);
            }
            if (ok) *(short4*)(lds_t + px * 260 + co0 + m * 16 + g * 4) = o;
        }
    }
    // fused pooling partials (row sums), deterministic shuffle reduce over l15
#pragma unroll
    for (int m = 0; m < 4; ++m)
#pragma unroll
        for (int j = 0; j < 4; ++j) {
            float r = rs[m][j];
            r += __shfl_xor(r, 1);
            r += __shfl_xor(r, 2);
            r += __shfl_xor(r, 4);
            r += __shfl_xor(r, 8);
            if (l15 == 0)
                pp[((size_t)b * H + h) * 256 + co0 + m * 16 + g * 4 + j] = r;
        }
    __syncthreads();
    // coalesced S^T store: [b][h*W+px][c]
    unsigned short* strow = ST + ((size_t)b * NPX + (size_t)h * W) * 256;
    for (int e = tid; e < W * 64; e += 256) {
        int px = e >> 6, c4 = e & 63;
        short4 v = *(const short4*)(lds_t + px * 260 + c4 * 4);
        *(short4*)(strow + (size_t)px * 256 + c4 * 4) = v;
    }
}

// ---------- pool: pp row-sums -> p (round-1-style) ----------
__global__ __launch_bounds__(256) void pool2_kernel(const float* __restrict__ pp,
                                                    float* __restrict__ p) {
    const int rows_[4] = {80, 40, 20, 10};
    const int base_[4] = {0, 327680, 491520, 573440};
    const float inv_[4] = {1.f / 6400.f, 1.f / 1600.f, 1.f / 400.f, 1.f / 100.f};
    int lvl = blockIdx.x >> 4;
    int b   = blockIdx.x & 15;
    int t   = threadIdx.x;
    int rows = rows_[lvl];
    const float* src = pp + base_[lvl] + ((size_t)b * rows) * 256 + t;
    float s = 0.f;
    for (int r = 0; r < rows; ++r) s += src[r * 256];
    p[(lvl * 16 + b) * 256 + t] = s * inv_[lvl];
}

// ---------- head stage 1 (round-9 validated) ----------
__global__ __launch_bounds__(256) void head1_kernel(
    const float* __restrict__ p,
    const float* __restrict__ clsw1, const float* __restrict__ clsb1,
    const float* __restrict__ regw1, const float* __restrict__ regb1,
    const float* __restrict__ lvlw,  const float* __restrict__ lvlb,
    const float* __restrict__ clsfb, const float* __restrict__ regfb,
    float* __restrict__ hb, float* __restrict__ beff)
{
    int lvl = blockIdx.x >> 4;
    int b   = blockIdx.x & 15;
    int t   = threadIdx.x;
    __shared__ float pl[256];
    __shared__ float lgl[4];
    __shared__ float attl;

    pl[t] = p[(lvl * 16 + b) * 256 + t];
    __syncthreads();

    float hval = 0.f;
    if (t < 64) {
        float a = clsb1[t];
        const float* wr = clsw1 + t * 256;
        for (int c2 = 0; c2 < 256; ++c2) a = fmaf(pl[c2], wr[c2], a);
        hval = a > 0.f ? a : 0.f;
    } else if (t < 128) {
        int j = t - 64;
        float a = regb1[j];
        const float* wr = regw1 + j * 256;
        for (int c2 = 0; c2 < 256; ++c2) a = fmaf(pl[c2], wr[c2], a);
        hval = a > 0.f ? a : 0.f;
    } else if (t < 132) {
        int j = t - 128;
        float a = lvlb[j];
        const float* wr = lvlw + j * 256;
        for (int c2 = 0; c2 < 256; ++c2) a = fmaf(pl[c2], wr[c2], a);
        lgl[j] = a;
    }
    __syncthreads();
    if (t == 0) {
        float m = fmaxf(fmaxf(lgl[0], lgl[1]), fmaxf(lgl[2], lgl[3]));
        float e0 = expf(lgl[0] - m), e1 = expf(lgl[1] - m);
        float e2 = expf(lgl[2] - m), e3 = expf(lgl[3] - m);
        float se = e0 + e1 + e2 + e3;
        float el = (lvl == 0) ? e0 : (lvl == 1) ? e1 : (lvl == 2) ? e2 : e3;
        attl = el / se;
    }
    __syncthreads();
    float att = attl;

    size_t base = (size_t)(lvl * 16 + b) * 136;
    if (t < 128) hb[base + t] = hval;
    else if (t == 128) hb[base + 128] = att;
    if (t < 84) {
        beff[(lvl * 16 + b) * 84 + t] = att * (t < 80 ? clsfb[t] : regfb[t - 80]);
    }
}

// ---------- head stage 2: weffM[lb][96][256] bf16 (m-major), rows 84..95 zero ----------
__global__ __launch_bounds__(256) void weff2_kernel(
    const float* __restrict__ hb,
    const float* __restrict__ clsw2, const float* __restrict__ clsb2,
    const float* __restrict__ regw2, const float* __restrict__ regb2,
    const float* __restrict__ clsfw, const float* __restrict__ regfw,
    unsigned short* __restrict__ weffM)
{
    int c = blockIdx.x;      // 0..255
    int t = threadIdx.x;
    __shared__ float wlds[84 * 64];
    __shared__ float hcs[64 * 65];
    __shared__ float hrs[64 * 65];
    __shared__ float atts[64];
    __shared__ float cst[84];

    {
        const float4* csrc = (const float4*)(clsw2 + (size_t)c * 80 * 64);
        float4* wd = (float4*)wlds;
        for (int e = t; e < 80 * 16; e += 256) wd[e] = csrc[e];
        const float4* rsrc = (const float4*)(regw2 + (size_t)c * 4 * 64);
        for (int e = t; e < 4 * 16; e += 256) wd[80 * 16 + e] = rsrc[e];
    }
    for (int e = t; e < 64 * 64; e += 256) {
        int lb = e >> 6, j = e & 63;
        hcs[lb * 65 + j] = hb[(size_t)lb * 136 + j];
        hrs[lb * 65 + j] = hb[(size_t)lb * 136 + 64 + j];
    }
    if (t < 64) atts[t] = hb[(size_t)t * 136 + 128];
    if (t < 84) {
        cst[t] = (t < 80) ? (clsb2[(size_t)c * 80 + t] + clsfw[(size_t)t * 256 + c])
                          : (regb2[(size_t)c * 4 + (t - 80)] + regfw[(size_t)(t - 80) * 256 + c]);
    }
    __syncthreads();

    int lb = t & 63;
    int kg0 = t >> 6;
    const float* hc = hcs + lb * 65;
    const float* hr = hrs + lb * 65;
    float att = atts[lb];
    unsigned short* ob = weffM + (size_t)lb * 24576;

    for (int kg = kg0; kg < 21; kg += 4) {
        const float* h = (kg == 20) ? hr : hc;
        const float* wr = wlds + kg * 4 * 64;
        float a0 = 0.f, a1 = 0.f, a2 = 0.f, a3 = 0.f;
#pragma unroll
        for (int j = 0; j < 64; ++j) {
            float hj = h[j];
            a0 = fmaf(hj, wr[j], a0);
            a1 = fmaf(hj, wr[64 + j], a1);
            a2 = fmaf(hj, wr[128 + j], a2);
            a3 = fmaf(hj, wr[192 + j], a3);
        }
        int k = kg * 4;
        ob[(size_t)(k + 0) * 256 + c] = f2bf(att * (cst[k + 0] + a0));
        ob[(size_t)(k + 1) * 256 + c] = f2bf(att * (cst[k + 1] + a1));
        ob[(size_t)(k + 2) * 256 + c] = f2bf(att * (cst[k + 2] + a2));
        ob[(size_t)(k + 3) * 256 + c] = f2bf(att * (cst[k + 3] + a3));
    }
    // zero rows 84..95
    for (int e = t; e < 64 * 12; e += 256) {
        int lb2 = e / 12, k2 = 84 + (e - lb2 * 12);
        weffM[(size_t)lb2 * 24576 + (size_t)k2 * 256 + c] = 0;
    }
}

// ---------- MFMA epilogue: out[k][px] = weffM[k][c] x S^T[px][c] + beff ----------
__global__ __launch_bounds__(512) void epilogue_mfma_kernel(
    const unsigned short* __restrict__ ST, const unsigned short* __restrict__ weffM,
    const float* __restrict__ beff, float* __restrict__ out)
{
    int bid = blockIdx.x;   // 560 blocks
    int lvl, tiles, rem;
    if (bid < 400)      { lvl = 0; tiles = 25; rem = bid; }
    else if (bid < 512) { lvl = 1; tiles = 7;  rem = bid - 400; }
    else if (bid < 544) { lvl = 2; tiles = 2;  rem = bid - 512; }
    else                { lvl = 3; tiles = 1;  rem = bid - 544; }
    const int npx_[4] = {6400, 1600, 400, 100};
    const long long stb_[4] = {0LL, 26214400LL, 32768000LL, 34406400LL};
    const int cb_[4]  = {0, 8192000, 10240000, 10752000};
    const int rb_[4]  = {10880000, 11289600, 11392000, 11417600};
    int npx  = npx_[lvl];
    int tile = rem % tiles;
    int b    = rem / tiles;
    int lb   = lvl * 16 + b;
    int px0  = tile * 256;

    int tid = threadIdx.x;
    int lane = tid & 63, wv = tid >> 6;   // 8 waves
    int g = lane >> 4, l15 = lane & 15;

    __shared__ unsigned short walds[96 * 256];  // [row][32 chunks of 8], swizzled
    __shared__ unsigned short slds[256 * 32];   // [px][4 chunks of 8], swizzled

    // stage weffM tile (once)
    const unsigned short* wsrc = weffM + (size_t)lb * 24576;
    for (int e = tid; e < 96 * 32; e += 512) {
        int row = e >> 5, ch = e & 31;
        bf16x8 v = *(const bf16x8*)(wsrc + (size_t)row * 256 + ch * 8);
        int chp = (ch & 16) | ((ch & 15) ^ (row & 15));
        *(bf16x8*)(walds + row * 256 + chp * 8) = v;
    }

    f32x4 acc[6][2];
#pragma unroll
    for (int m = 0; m < 6; ++m) { acc[m][0] = (f32x4)0.0f; acc[m][1] = (f32x4)0.0f; }

    const unsigned short* stB = ST + stb_[lvl] + ((size_t)b * npx + px0) * 256;

    for (int kk = 0; kk < 8; ++kk) {
        __syncthreads();
        for (int pr = tid; pr < 1024; pr += 512) {
            int px = pr >> 2, e = pr & 3;
            bf16x8 v = *(const bf16x8*)(stB + (size_t)px * 256 + kk * 32 + e * 8);
            *(bf16x8*)(slds + px * 32 + ((e ^ ((px >> 1) & 3)) * 8)) = v;
        }
        __syncthreads();

        bf16x8 af[6];
#pragma unroll
        for (int m = 0; m < 6; ++m) {
            int row = m * 16 + l15;
            int chA = kk * 4 + g;
            int chp = (chA & 16) | ((chA & 15) ^ (row & 15));
            af[m] = *(const bf16x8*)(walds + row * 256 + chp * 8);
        }
#pragma unroll
        for (int nn = 0; nn < 2; ++nn) {
            int px = wv * 32 + nn * 16 + l15;
            bf16x8 bf = *(const bf16x8*)(slds + px * 32 + ((g ^ ((px >> 1) & 3)) * 8));
#pragma unroll
            for (int m = 0; m < 6; ++m)
                acc[m][nn] = __builtin_amdgcn_mfma_f32_16x16x32_bf16(af[m], bf, acc[m][nn], 0, 0, 0);
        }
    }

    const float* lbeff = beff + (size_t)lb * 84;
#pragma unroll
    for (int m = 0; m < 6; ++m) {
#pragma unroll
        for (int nn = 0; nn < 2; ++nn) {
            int px = px0 + wv * 32 + nn * 16 + l15;
            if (px >= npx) continue;
#pragma unroll
            for (int j = 0; j < 4; ++j) {
                int k = m * 16 + g * 4 + j;
                if (k >= 84) continue;
                float v = acc[m][nn][j] + lbeff[k];
                float* op;
                if (k < 80) op = out + cb_[lvl] + ((size_t)b * 80 + k) * npx + px;
                else        op = out + rb_[lvl] + ((size_t)b * 4 + (k - 80)) * npx + px;
                *op = v;
            }
        }
    }
}

extern "C" void kernel_launch(void* const* d_in, const int* in_sizes, int n_in,
                              void* d_out, int out_size, void* d_ws, size_t ws_size,
                              hipStream_t stream) {
    (void)in_sizes; (void)n_in; (void)out_size; (void)ws_size;
    const float* feat0  = (const float*)d_in[0];
    const float* feat1  = (const float*)d_in[1];
    const float* feat2  = (const float*)d_in[2];
    const float* feat3  = (const float*)d_in[3];
    const float* conv_w = (const float*)d_in[4];
    const float* conv_b = (const float*)d_in[5];
    const float* clsw1  = (const float*)d_in[6];
    const float* clsb1  = (const float*)d_in[7];
    const float* clsw2  = (const float*)d_in[8];
    const float* clsb2  = (const float*)d_in[9];
    const float* regw1  = (const float*)d_in[10];
    const float* regb1  = (const float*)d_in[11];
    const float* regw2  = (const float*)d_in[12];
    const float* regb2  = (const float*)d_in[13];
    const float* lvlw   = (const float*)d_in[14];
    const float* lvlb   = (const float*)d_in[15];
    const float* clsfw  = (const float*)d_in[16];
    const float* clsfb  = (const float*)d_in[17];
    const float* regfw  = (const float*)d_in[18];
    const float* regfb  = (const float*)d_in[19];

    char* ws = (char*)d_ws;
    unsigned short* WT3   = (unsigned short*)(ws + OFFB_WT3);
    unsigned short* PT    = (unsigned short*)(ws + OFFB_PT);
    unsigned short* weffM = (unsigned short*)(ws + OFFB_WEFFM);
    unsigned short* ST    = (unsigned short*)(ws + OFFB_ST);
    float*          pp    = (float*)(ws + OFFB_PP);
    float*          p     = (float*)(ws + OFFB_P);
    float*          beff  = (float*)(ws + OFFB_BEFF);
    float*          hb    = (float*)(ws + OFFB_HB);
    float* out = (float*)d_out;

    unsigned short* PT0 = PT;
    unsigned short* PT1 = PT + 27541504LL;
    unsigned short* PT2 = PT + 34766848LL;
    unsigned short* PT3 = PT + 36749312LL;
    unsigned short* ST0 = ST;
    unsigned short* ST1 = ST + 26214400LL;
    unsigned short* ST2 = ST + 32768000LL;
    unsigned short* ST3 = ST + 34406400LL;
    float* pp0 = pp;
    float* pp1 = pp + 327680;
    float* pp2 = pp + 491520;
    float* pp3 = pp + 573440;

    hipLaunchKernelGGL(prep_w_kernel, dim3(256), dim3(256), 0, stream, conv_w, WT3);

    hipLaunchKernelGGL((pad_transpose_kernel<80,80>), dim3(16*82), dim3(256), 0, stream, feat0, PT0);
    hipLaunchKernelGGL((pad_transpose_kernel<40,40>), dim3(16*42), dim3(256), 0, stream, feat1, PT1);
    hipLaunchKernelGGL((pad_transpose_kernel<20,20>), dim3(16*22), dim3(256), 0, stream, feat2, PT2);
    hipLaunchKernelGGL((pad_transpose_kernel<10,10>), dim3(16*12), dim3(256), 0, stream, feat3, PT3);

    hipLaunchKernelGGL((conv_mfma_kernel<80,80,5,84>), dim3(16*80), dim3(256), 0, stream, PT0, WT3, conv_b, ST0, pp0);
    hipLaunchKernelGGL((conv_mfma_kernel<40,40,3,52>), dim3(16*40), dim3(256), 0, stream, PT1, WT3, conv_b, ST1, pp1);
    hipLaunchKernelGGL((conv_mfma_kernel<20,20,2,36>), dim3(16*20), dim3(256), 0, stream, PT2, WT3, conv_b, ST2, pp2);
    hipLaunchKernelGGL((conv_mfma_kernel<10,10,1,20>), dim3(16*10), dim3(256), 0, stream, PT3, WT3, conv_b, ST3, pp3);

    hipLaunchKernelGGL(pool2_kernel, dim3(64), dim3(256), 0, stream, pp, p);
    hipLaunchKernelGGL(head1_kernel, dim3(64), dim3(256), 0, stream, p,
                       clsw1, clsb1, regw1, regb1, lvlw, lvlb, clsfb, regfb, hb, beff);
    hipLaunchKernelGGL(weff2_kernel, dim3(256), dim3(256), 0, stream, hb,
                       clsw2, clsb2, regw2, regb2, clsfw, regfw, weffM);
    hipLaunchKernelGGL(epilogue_mfma_kernel, dim3(560), dim3(512), 0, stream, ST, weffM, beff, out);
}